// Round 2
// baseline (1590.723 us; speedup 1.0000x reference)
//
#include <hip/hip_runtime.h>
#include <stdint.h>

typedef unsigned short u16;
typedef unsigned int   u32;
typedef __attribute__((ext_vector_type(8))) short bf16x8;
typedef __attribute__((ext_vector_type(4))) float f32x4;

#define NN 20000
#define NE 320000
#define HD 256
#define BD 64
#define MSGIN 576

// ws layout (bytes) — total < 32 MB
#define WS_HBA   0u          // 20,480,000  fp32 h ping buffer
#define WS_HBF   20480000u   // 10,240,000  bf16 mirror of current h
#define WS_W1T   30720000u   // 884,736     bf16 W1^T [3][256][576]
#define WS_W2T   31604736u   // 393,216     bf16 W2^T [3][256][256]
#define WS_GATE  31997952u   // 64          15 gate values
#define WS_POOL  31998016u   // 1,024       column sums
#define WS_FGV   31999040u   // 256         fg values

__device__ __forceinline__ u16 f2bf(float f){
  u32 u = __float_as_uint(f);
  u += 0x7fffu + ((u >> 16) & 1u);
  return (u16)(u >> 16);
}
__device__ __forceinline__ u32 pk2(float a, float b){
  return (u32)f2bf(a) | ((u32)f2bf(b) << 16);
}

// ---- one-time weight transpose+bf16 ----
__global__ void conv_w1_k(const float* __restrict__ w, u16* __restrict__ wt){
  int i = blockIdx.x*256 + threadIdx.x;
  if (i >= 3*MSGIN*HD) return;
  int l = i / (MSGIN*HD);
  int r = i - l*(MSGIN*HD);
  int k = r >> 8;          // in-dim 0..575
  int n = r & 255;         // out-dim
  wt[(size_t)l*HD*MSGIN + (size_t)n*MSGIN + k] = f2bf(w[i]);
}

__global__ void conv_w2_k(const float* __restrict__ w, u16* __restrict__ wt){
  int i = blockIdx.x*256 + threadIdx.x;
  if (i >= 3*HD*HD) return;
  int l = i >> 16;
  int r = i & 65535;
  int k = r >> 8;
  int n = r & 255;
  wt[(size_t)l*HD*HD + (size_t)n*HD + k] = f2bf(w[i]);
}

// ---- gate table (15 values) + zero pooled ----
__global__ void gate_zero_k(const float* __restrict__ bond_table,
                            const float* __restrict__ att_w,
                            const float* __restrict__ att_b,
                            float* __restrict__ gate_tab,
                            float* __restrict__ pooled){
  int t = threadIdx.x;
  if (t < 15){
    int l = t / 5, b = t - 5*l;
    float s = att_b[l];
    for (int d = 0; d < BD; ++d) s += bond_table[b*BD + d] * att_w[l*BD + d];
    gate_tab[t] = 1.0f / (1.0f + __expf(-s));
  }
  for (int i = t; i < HD; i += 64) pooled[i] = 0.0f;
}

// ---- node embedding init + atom_types output ----
__global__ void init_embed_k(const float* __restrict__ x,
                             const float* __restrict__ atom_table,
                             const float* __restrict__ charge_table,
                             const float* __restrict__ hybrid_table,
                             float* __restrict__ h0,
                             float* __restrict__ out_at){
  int n = blockIdx.x, c = threadIdx.x;
  int at = (int)x[n*3 + 0]; at = at < 0 ? 0 : (at > 10 ? 10 : at);
  int hy = (int)x[n*3 + 1]; hy = hy < 0 ? 0 : (hy > 7 ? 7 : hy);
  int fc = (int)x[n*3 + 2] + 3; fc = fc < 0 ? 0 : (fc > 6 ? 6 : fc);
  float v = 0.0f;
  if (c < 64)       v = atom_table[at*64 + c];
  else if (c < 96)  v = charge_table[fc*32 + (c - 64)];
  else if (c < 128) v = hybrid_table[hy*32 + (c - 96)];
  h0[(size_t)n*HD + c] = v;
  if (c == 0) out_at[n] = (float)at;
}

// ---- per-layer: hn = hc (fp32 copy), hbf = bf16(hc) ----
__global__ void prep_k(const float* __restrict__ hc,
                       float* __restrict__ hn,
                       u16* __restrict__ hbf){
  int i = blockIdx.x*256 + threadIdx.x;      // one float4 per thread
  float4 v = ((const float4*)hc)[i];
  ((float4*)hn)[i] = v;
  uint2 u; u.x = pk2(v.x, v.y); u.y = pk2(v.z, v.w);
  ((uint2*)hbf)[i] = u;
}

// ---- fused edge MLP: 64 edges/block, 4 waves, full 256-col output ----
__launch_bounds__(256, 2)
__global__ void edge_mlp_k(const int* __restrict__ eidx,
                           const float* __restrict__ eattr,
                           const u16* __restrict__ hbf,
                           const float* __restrict__ bond_table,
                           const u16* __restrict__ w1t,
                           const u16* __restrict__ w2t,
                           const float* __restrict__ b1g,
                           const float* __restrict__ b2g,
                           const float* __restrict__ gate_tab,
                           float* __restrict__ hn,
                           int layer){
  __shared__ u16 a_lds[64*40];     // 64 edges x 32 k, stride 40
  __shared__ u16 b_lds[256*40];    // 256 cols x 32 k, stride 40
  __shared__ u16 t_lds[64*264];    // 64 edges x 256 mid, stride 264

  const int tid = threadIdx.x;
  const int eBase = blockIdx.x * 64;

  const int w    = tid >> 6;
  const int lane = tid & 63;
  const int g    = lane >> 4;
  const int lr   = lane & 15;
  const int rstage = tid >> 2;   // edge row this thread stages (0..63)
  const int q      = tid & 3;    // which 8-elem chunk of the 32-k step

  // per-thread edge metadata straight from global (L1-hot), clamped
  const int eS = eBase + rstage;
  int rI  = eidx[eS];       rI  = rI  < 0 ? 0 : (rI  >= NN ? NN-1 : rI);
  int cI  = eidx[NE + eS];  cI  = cI  < 0 ? 0 : (cI  >= NN ? NN-1 : cI);
  int btI = (int)eattr[eS]; btI = btI < 0 ? 0 : (btI > 4 ? 4 : btI);

  const u16* w1p = w1t + (size_t)layer*HD*MSGIN + (size_t)tid*MSGIN;
  const u16* w2p = w2t + (size_t)layer*HD*HD   + (size_t)tid*HD;

  f32x4 acc[4][4];
  for (int mi = 0; mi < 4; ++mi)
    for (int nj = 0; nj < 4; ++nj)
      acc[mi][nj] = (f32x4){0.f, 0.f, 0.f, 0.f};

  // ---- GEMM1: [64x576] @ [576x256] ----
  for (int ks = 0; ks < 18; ++ks){
    __syncthreads();
    { // stage A (gather)
      int k0 = ks*32 + q*8;
      uint4 av;
      if (k0 < 512){
        const u16* src = hbf + (size_t)(k0 < 256 ? rI : cI)*HD + (k0 & 255);
        av = *(const uint4*)src;
      } else {
        const float* bp = bond_table + btI*BD + (k0 - 512);
        float4 f0 = *(const float4*)bp;
        float4 f1 = *(const float4*)(bp + 4);
        av.x = pk2(f0.x, f0.y); av.y = pk2(f0.z, f0.w);
        av.z = pk2(f1.x, f1.y); av.w = pk2(f1.z, f1.w);
      }
      *(uint4*)(a_lds + rstage*40 + q*8) = av;
    }
    { // stage B: col = tid, 32 k values
      const u16* src = w1p + ks*32;
      uint4 s0 = *(const uint4*)(src);
      uint4 s1 = *(const uint4*)(src + 8);
      uint4 s2 = *(const uint4*)(src + 16);
      uint4 s3 = *(const uint4*)(src + 24);
      u16* dst = b_lds + tid*40;
      *(uint4*)(dst)      = s0;
      *(uint4*)(dst + 8)  = s1;
      *(uint4*)(dst + 16) = s2;
      *(uint4*)(dst + 24) = s3;
    }
    __syncthreads();
    bf16x8 af[4], bfr[4];
    for (int mi = 0; mi < 4; ++mi)
      af[mi] = *(const bf16x8*)(a_lds + (mi*16 + lr)*40 + g*8);
    for (int nj = 0; nj < 4; ++nj)
      bfr[nj] = *(const bf16x8*)(b_lds + (w*64 + nj*16 + lr)*40 + g*8);
    for (int mi = 0; mi < 4; ++mi)
      for (int nj = 0; nj < 4; ++nj)
        acc[mi][nj] = __builtin_amdgcn_mfma_f32_16x16x32_bf16(af[mi], bfr[nj], acc[mi][nj], 0, 0, 0);
  }

  __syncthreads();
  // bias + relu -> t_lds (bf16)
  {
    float b1v[4];
    for (int nj = 0; nj < 4; ++nj) b1v[nj] = b1g[layer*HD + w*64 + nj*16 + lr];
    for (int mi = 0; mi < 4; ++mi)
      for (int nj = 0; nj < 4; ++nj){
        int colt = w*64 + nj*16 + lr;
        for (int p = 0; p < 4; ++p){
          float v = acc[mi][nj][p] + b1v[nj];
          v = v > 0.f ? v : 0.f;
          t_lds[(mi*16 + g*4 + p)*264 + colt] = f2bf(v);
        }
        acc[mi][nj] = (f32x4){0.f, 0.f, 0.f, 0.f};
      }
  }

  // ---- GEMM2: [64x256] @ [256x256] ----
  for (int ks = 0; ks < 8; ++ks){
    __syncthreads();
    {
      const u16* src = w2p + ks*32;
      uint4 s0 = *(const uint4*)(src);
      uint4 s1 = *(const uint4*)(src + 8);
      uint4 s2 = *(const uint4*)(src + 16);
      uint4 s3 = *(const uint4*)(src + 24);
      u16* dst = b_lds + tid*40;
      *(uint4*)(dst)      = s0;
      *(uint4*)(dst + 8)  = s1;
      *(uint4*)(dst + 16) = s2;
      *(uint4*)(dst + 24) = s3;
    }
    __syncthreads();
    bf16x8 af[4], bfr[4];
    for (int mi = 0; mi < 4; ++mi)
      af[mi] = *(const bf16x8*)(t_lds + (mi*16 + lr)*264 + ks*32 + g*8);
    for (int nj = 0; nj < 4; ++nj)
      bfr[nj] = *(const bf16x8*)(b_lds + (w*64 + nj*16 + lr)*40 + g*8);
    for (int mi = 0; mi < 4; ++mi)
      for (int nj = 0; nj < 4; ++nj)
        acc[mi][nj] = __builtin_amdgcn_mfma_f32_16x16x32_bf16(af[mi], bfr[nj], acc[mi][nj], 0, 0, 0);
  }

  // ---- epilogue: +b2, *gate, atomic scatter-add into hn ----
  {
    float b2v[4];
    for (int nj = 0; nj < 4; ++nj) b2v[nj] = b2g[layer*HD + w*64 + nj*16 + lr];
    for (int mi = 0; mi < 4; ++mi){
      for (int p = 0; p < 4; ++p){
        int re = mi*16 + g*4 + p;
        int ee = eBase + re;
        int ridx = eidx[ee];      ridx = ridx < 0 ? 0 : (ridx >= NN ? NN-1 : ridx);
        int bt2  = (int)eattr[ee]; bt2 = bt2 < 0 ? 0 : (bt2 > 4 ? 4 : bt2);
        float gt = gate_tab[layer*5 + bt2];
        float* dst = hn + (size_t)ridx*HD;
        for (int nj = 0; nj < 4; ++nj){
          int colt = w*64 + nj*16 + lr;
          atomicAdd(dst + colt, (acc[mi][nj][p] + b2v[nj]) * gt);
        }
      }
    }
  }
}

// ---- column sums for pooling (h already lives in out) ----
__global__ void pool_k(const float* __restrict__ h,
                       float* __restrict__ pooled){
  int c = threadIdx.x;
  int r0 = blockIdx.x * 250;
  float s = 0.f;
  for (int r = r0; r < r0 + 250; ++r)
    s += h[(size_t)r*HD + c];
  atomicAdd(&pooled[c], s);
}

// ---- fg = mean(h) @ fg_w + fg_b  (64 values) ----
__global__ void fg_k(const float* __restrict__ pooled,
                     const float* __restrict__ fg_w,
                     const float* __restrict__ fg_b,
                     float* __restrict__ fg_vals){
  int o = threadIdx.x;          // 0..63
  int k = o >> 4, j = o & 15;
  float s = 0.f;
  for (int d = 0; d < HD; ++d) s += pooled[d] * fg_w[(size_t)k*HD*16 + d*16 + j];
  fg_vals[o] = s / (float)NN + fg_b[k*16 + j];
}

__global__ void bcast_fg_k(const float* __restrict__ fg_vals,
                           float* __restrict__ out_fg){
  __shared__ float fv[64];
  if (threadIdx.x < 64) fv[threadIdx.x] = fg_vals[threadIdx.x];
  __syncthreads();
  int i = blockIdx.x*256 + threadIdx.x;
  out_fg[i] = fv[i & 63];
}

// ---- chemical properties MLP: relu(h@W1+b1)@W2+b2 ----
__global__ void props_k(const float* __restrict__ h,
                        const float* __restrict__ w1,
                        const float* __restrict__ b1,
                        const float* __restrict__ w2,
                        const float* __restrict__ b2,
                        float* __restrict__ outp){
  __shared__ float hrow[256];
  __shared__ float tbuf[128];
  int n = blockIdx.x, c = threadIdx.x;
  hrow[c]       = h[(size_t)n*HD + c];
  hrow[c + 128] = h[(size_t)n*HD + 128 + c];
  __syncthreads();
  float s = b1[c];
  for (int d = 0; d < 256; ++d) s += hrow[d] * w1[d*128 + c];
  tbuf[c] = s > 0.f ? s : 0.f;
  __syncthreads();
  if (c < 32){
    float s2 = b2[c];
    for (int d = 0; d < 128; ++d) s2 += tbuf[d] * w2[d*32 + c];
    outp[(size_t)n*32 + c] = s2;
  }
}

extern "C" void kernel_launch(void* const* d_in, const int* in_sizes, int n_in,
                              void* d_out, int out_size, void* d_ws, size_t ws_size,
                              hipStream_t stream) {
  const float* x            = (const float*)d_in[0];
  const int*   eidx         = (const int*)  d_in[1];
  const float* eattr        = (const float*)d_in[2];
  const float* atom_table   = (const float*)d_in[4];
  const float* charge_table = (const float*)d_in[5];
  const float* hybrid_table = (const float*)d_in[6];
  const float* bond_table   = (const float*)d_in[7];
  const float* gw1          = (const float*)d_in[8];
  const float* gb1          = (const float*)d_in[9];
  const float* gw2          = (const float*)d_in[10];
  const float* gb2          = (const float*)d_in[11];
  const float* attw         = (const float*)d_in[12];
  const float* attb         = (const float*)d_in[13];
  const float* pw1          = (const float*)d_in[14];
  const float* pb1          = (const float*)d_in[15];
  const float* pw2          = (const float*)d_in[16];
  const float* pb2          = (const float*)d_in[17];
  const float* fgw          = (const float*)d_in[18];
  const float* fgb          = (const float*)d_in[19];

  float* out       = (float*)d_out;
  float* out_h     = out;                          // final h lands here
  float* out_props = out + (size_t)NN*HD;
  float* out_fg    = out_props + (size_t)NN*32;
  float* out_at    = out_fg + (size_t)NN*64;

  char* ws = (char*)d_ws;
  float* hbA      = (float*)(ws + WS_HBA);
  u16*   hbf      = (u16*)  (ws + WS_HBF);
  u16*   w1t      = (u16*)  (ws + WS_W1T);
  u16*   w2t      = (u16*)  (ws + WS_W2T);
  float* gate_tab = (float*)(ws + WS_GATE);
  float* pooled   = (float*)(ws + WS_POOL);
  float* fg_vals  = (float*)(ws + WS_FGV);

  conv_w1_k<<<1728, 256, 0, stream>>>(gw1, w1t);
  conv_w2_k<<<768, 256, 0, stream>>>(gw2, w2t);
  gate_zero_k<<<1, 64, 0, stream>>>(bond_table, attw, attb, gate_tab, pooled);
  init_embed_k<<<NN, 256, 0, stream>>>(x, atom_table, charge_table, hybrid_table, hbA, out_at);

  // ping-pong: A -> out_h -> A -> out_h (final h in out_h)
  float* hc = hbA;
  float* hn = out_h;
  for (int l = 0; l < 3; ++l){
    prep_k<<<5000, 256, 0, stream>>>(hc, hn, hbf);
    edge_mlp_k<<<5000, 256, 0, stream>>>(eidx, eattr, hbf, bond_table, w1t, w2t,
                                         gb1, gb2, gate_tab, hn, l);
    float* t = hc; hc = hn; hn = t;
  }
  // after 3 swaps hc == out_h

  pool_k<<<80, 256, 0, stream>>>(out_h, pooled);
  fg_k<<<1, 64, 0, stream>>>(pooled, fgw, fgb, fg_vals);
  bcast_fg_k<<<5000, 256, 0, stream>>>(fg_vals, out_fg);
  props_k<<<NN, 128, 0, stream>>>(out_h, pw1, pb1, pw2, pb2, out_props);
}

// Round 3
// 791.174 us; speedup vs baseline: 2.0106x; 2.0106x over previous
//
#include <hip/hip_runtime.h>
#include <stdint.h>

typedef unsigned short u16;
typedef unsigned int   u32;
typedef __attribute__((ext_vector_type(8))) short bf16x8;
typedef __attribute__((ext_vector_type(4))) float f32x4;

#define NN 20000
#define NE 320000
#define HD 256
#define BD 64

// ws layout (bytes) — total ~23.1 MB
#define WS_PRE   0u           // bf16 [NN][512]  (pre1|pre2)   20,480,000
#define WS_W1T   20480000u    // bf16 [3][512][256]               786,432
#define WS_W2T   21266432u    // bf16 [3][256][256]               393,216
#define WS_PREB  21659648u    // f32  [3][5][256]                  15,360
#define WS_GATE  21675008u    // f32  [15]
#define WS_POOL  21675072u    // f32  [256]
#define WS_FGV   21676096u    // f32  [64]
#define WS_CNT   21676352u    // int  [NN]  counts->cursor         80,000
#define WS_EORD  21756352u    // int  [NE]  row-sorted edge ids 1,280,000

__device__ __forceinline__ u16 f2bf(float f){
  u32 u = __float_as_uint(f);
  u += 0x7fffu + ((u >> 16) & 1u);
  return (u16)(u >> 16);
}
__device__ __forceinline__ u32 pk2(float a, float b){
  return (u32)f2bf(a) | ((u32)f2bf(b) << 16);
}
__device__ __forceinline__ float bf2f(u16 u){
  return __uint_as_float((u32)u << 16);
}

// ---- W1[0:512] -> bf16 transposed [3][512 out-or-col][256 k] ----
// col c<256: pre1 (uses W1 rows k), c>=256: pre2 (uses W1 rows 256+k)
__global__ void conv_w1ab_k(const float* __restrict__ w, u16* __restrict__ wt){
  int i = blockIdx.x*256 + threadIdx.x;
  if (i >= 3*512*256) return;
  int l = i >> 17;
  int r = i & 131071;
  int c = r >> 8;          // 0..511
  int k = r & 255;
  int srow = (c < 256) ? k : (256 + k);
  wt[i] = f2bf(w[(l*576 + srow)*256 + (c & 255)]);
}

// ---- W2 -> bf16 transposed [3][256 out][256 k] ----
__global__ void conv_w2_k(const float* __restrict__ w, u16* __restrict__ wt){
  int i = blockIdx.x*256 + threadIdx.x;
  if (i >= 3*HD*HD) return;
  int l = i >> 16;
  int r = i & 65535;
  int k = r >> 8;
  int n = r & 255;
  wt[(size_t)l*HD*HD + (size_t)n*HD + k] = f2bf(w[i]);
}

// ---- preb[l][bt][c] = b1[l][c] + bond[bt] @ W1[512:576] ----
__global__ void preb_k(const float* __restrict__ bond_table,
                       const float* __restrict__ gw1,
                       const float* __restrict__ gb1,
                       float* __restrict__ preb){
  int l = blockIdx.x, c = threadIdx.x;
  for (int bt = 0; bt < 5; ++bt){
    float s = gb1[l*HD + c];
    for (int d = 0; d < BD; ++d)
      s += bond_table[bt*BD + d] * gw1[(l*576 + 512 + d)*256 + c];
    preb[(l*5 + bt)*256 + c] = s;
  }
}

// ---- gate table (15 values) + zero pooled ----
__global__ void gate_zero_k(const float* __restrict__ bond_table,
                            const float* __restrict__ att_w,
                            const float* __restrict__ att_b,
                            float* __restrict__ gate_tab,
                            float* __restrict__ pooled){
  int t = threadIdx.x;
  if (t < 15){
    int l = t / 5, b = t - 5*l;
    float s = att_b[l];
    for (int d = 0; d < BD; ++d) s += bond_table[b*BD + d] * att_w[l*BD + d];
    gate_tab[t] = 1.0f / (1.0f + __expf(-s));
  }
  for (int i = t; i < HD; i += 64) pooled[i] = 0.0f;
}

__global__ void zero_counts_k(int* __restrict__ cnt){
  int i = blockIdx.x*256 + threadIdx.x;
  if (i < NN) cnt[i] = 0;
}

// ---- node embedding init (h lives in out) + atom_types output ----
__global__ void init_embed_k(const float* __restrict__ x,
                             const float* __restrict__ atom_table,
                             const float* __restrict__ charge_table,
                             const float* __restrict__ hybrid_table,
                             float* __restrict__ h0,
                             float* __restrict__ out_at){
  int n = blockIdx.x, c = threadIdx.x;
  int at = (int)x[n*3 + 0]; at = at < 0 ? 0 : (at > 10 ? 10 : at);
  int hy = (int)x[n*3 + 1]; hy = hy < 0 ? 0 : (hy > 7 ? 7 : hy);
  int fc = (int)x[n*3 + 2] + 3; fc = fc < 0 ? 0 : (fc > 6 ? 6 : fc);
  float v = 0.0f;
  if (c < 64)       v = atom_table[at*64 + c];
  else if (c < 96)  v = charge_table[fc*32 + (c - 64)];
  else if (c < 128) v = hybrid_table[hy*32 + (c - 96)];
  h0[(size_t)n*HD + c] = v;
  if (c == 0) out_at[n] = (float)at;
}

// ---- counting sort by row: hist, scan, scatter ----
__global__ void hist_k(const int* __restrict__ eidx, int* __restrict__ cnt){
  int e = blockIdx.x*256 + threadIdx.x;       // grid exactly covers NE
  int r = eidx[e]; r = r < 0 ? 0 : (r >= NN ? NN-1 : r);
  atomicAdd(&cnt[r], 1);
}

__launch_bounds__(1024)
__global__ void scan_k(int* __restrict__ cnt){   // counts -> exclusive prefix (cursor), in place
  __shared__ int part[1024];
  int t = threadIdx.x;
  int base = t*20;
  int loc[20];
  int s = 0;
  #pragma unroll
  for (int j = 0; j < 20; ++j){
    int idx = base + j;
    int v = (idx < NN) ? cnt[idx] : 0;
    loc[j] = v; s += v;
  }
  part[t] = s; __syncthreads();
  for (int off = 1; off < 1024; off <<= 1){
    int v = (t >= off) ? part[t-off] : 0;
    __syncthreads();
    part[t] += v;
    __syncthreads();
  }
  int run = part[t] - s;
  #pragma unroll
  for (int j = 0; j < 20; ++j){
    int idx = base + j;
    if (idx < NN){ cnt[idx] = run; run += loc[j]; }
  }
}

__global__ void scatter_k(const int* __restrict__ eidx, int* __restrict__ cur,
                          int* __restrict__ eord){
  int e = blockIdx.x*256 + threadIdx.x;
  int r = eidx[e]; r = r < 0 ? 0 : (r >= NN ? NN-1 : r);
  int pos = atomicAdd(&cur[r], 1);
  if (pos >= 0 && pos < NE) eord[pos] = e;
}

// ---- pre = bf16( h @ [W1a|W1b] ) : [NN][512] ----
__launch_bounds__(256, 2)
__global__ void pre_k(const float* __restrict__ h,
                      const u16* __restrict__ w1t,
                      u16* __restrict__ pre, int layer){
  __shared__ u16 a_lds[64*40];
  __shared__ u16 b_lds[256*40];
  const int tid = threadIdx.x;
  const int n0 = blockIdx.x * 64;
  const int half = blockIdx.y;
  const int w = tid >> 6, lane = tid & 63, g = lane >> 4, lr = lane & 15;
  const int rstage = tid >> 2, q = tid & 3;
  int arow = n0 + rstage; if (arow >= NN) arow = NN-1;
  const float* hrow = h + (size_t)arow*HD;
  const u16* bp = w1t + ((size_t)layer*512 + (size_t)half*256 + tid)*256;

  f32x4 acc[4][4];
  for (int mi = 0; mi < 4; ++mi)
    for (int nj = 0; nj < 4; ++nj)
      acc[mi][nj] = (f32x4){0.f,0.f,0.f,0.f};

  for (int ks = 0; ks < 8; ++ks){
    __syncthreads();
    { // A: fp32 h -> bf16
      const float* src = hrow + ks*32 + q*8;
      float4 f0 = *(const float4*)src;
      float4 f1 = *(const float4*)(src + 4);
      uint4 av;
      av.x = pk2(f0.x,f0.y); av.y = pk2(f0.z,f0.w);
      av.z = pk2(f1.x,f1.y); av.w = pk2(f1.z,f1.w);
      *(uint4*)(a_lds + rstage*40 + q*8) = av;
    }
    { // B
      const u16* src = bp + ks*32;
      uint4 s0 = *(const uint4*)(src);
      uint4 s1 = *(const uint4*)(src + 8);
      uint4 s2 = *(const uint4*)(src + 16);
      uint4 s3 = *(const uint4*)(src + 24);
      u16* dst = b_lds + tid*40;
      *(uint4*)(dst)      = s0;
      *(uint4*)(dst + 8)  = s1;
      *(uint4*)(dst + 16) = s2;
      *(uint4*)(dst + 24) = s3;
    }
    __syncthreads();
    bf16x8 af[4], bfr[4];
    for (int mi = 0; mi < 4; ++mi)
      af[mi] = *(const bf16x8*)(a_lds + (mi*16 + lr)*40 + g*8);
    for (int nj = 0; nj < 4; ++nj)
      bfr[nj] = *(const bf16x8*)(b_lds + (w*64 + nj*16 + lr)*40 + g*8);
    for (int mi = 0; mi < 4; ++mi)
      for (int nj = 0; nj < 4; ++nj)
        acc[mi][nj] = __builtin_amdgcn_mfma_f32_16x16x32_bf16(af[mi], bfr[nj], acc[mi][nj], 0, 0, 0);
  }

  for (int mi = 0; mi < 4; ++mi)
    for (int nj = 0; nj < 4; ++nj)
      for (int p = 0; p < 4; ++p){
        int re = mi*16 + g*4 + p;
        int n = n0 + re;
        if (n < NN)
          pre[(size_t)n*512 + half*256 + w*64 + nj*16 + lr] = f2bf(acc[mi][nj][p]);
      }
}

// ---- fused edge kernel: gather pre -> relu -> GEMM2 -> gate -> segmented reduce -> atomics
__launch_bounds__(256, 2)
__global__ void edge_msg_k(const int* __restrict__ eidx,
                           const float* __restrict__ eattr,
                           const int* __restrict__ eord,
                           const u16* __restrict__ pre,
                           const float* __restrict__ prebg,
                           const u16* __restrict__ w2t,
                           const float* __restrict__ b2g,
                           const float* __restrict__ gate_tab,
                           float* __restrict__ h,
                           int layer){
  __shared__ u16 b_lds[256*40];     // 20,480 B  W2 staging
  __shared__ u16 t_lds[256*72];     // 36,864 B  t [64][stride 264] then msgs [256 col][stride 72]
  __shared__ float preb_lds[5*256]; //  5,120 B
  __shared__ int   row_l[64];
  __shared__ int   col_l[64];
  __shared__ int   bt_l[64];
  __shared__ float gate_l[64];

  const int tid = threadIdx.x;
  const int eBase = blockIdx.x * 64;
  const int w = tid >> 6, lane = tid & 63, g = lane >> 4, lr = lane & 15;
  const int rstage = tid >> 2, q = tid & 3;

  if (tid < 64){
    int e = eord[eBase + tid]; e = e < 0 ? 0 : (e >= NE ? NE-1 : e);
    int r  = eidx[e];       r  = r  < 0 ? 0 : (r  >= NN ? NN-1 : r);
    int c  = eidx[NE + e];  c  = c  < 0 ? 0 : (c  >= NN ? NN-1 : c);
    int bt = (int)eattr[e]; bt = bt < 0 ? 0 : (bt > 4 ? 4 : bt);
    row_l[tid] = r; col_l[tid] = c; bt_l[tid] = bt;
    gate_l[tid] = gate_tab[layer*5 + bt];
  }
  for (int j = 0; j < 5; ++j)
    preb_lds[j*256 + tid] = prebg[(layer*5 + j)*256 + tid];
  __syncthreads();

  // ---- t = relu(pre1[row] + pre2[col] + preb[bt]) -> bf16 t_lds[edge][mid] ----
  {
    int rI = row_l[rstage], cI = col_l[rstage], btI = bt_l[rstage];
    const u16* p1 = pre + (size_t)rI*512;
    const u16* p2 = pre + (size_t)cI*512 + 256;
    const float* pb = preb_lds + btI*256;
    for (int it = 0; it < 8; ++it){
      int c0 = q*64 + it*8;
      bf16x8 v1 = *(const bf16x8*)(p1 + c0);
      bf16x8 v2 = *(const bf16x8*)(p2 + c0);
      float pv[8];
      *(float4*)(pv)     = *(const float4*)(pb + c0);
      *(float4*)(pv + 4) = *(const float4*)(pb + c0 + 4);
      float f[8];
      #pragma unroll
      for (int j = 0; j < 8; ++j){
        float s = bf2f((u16)v1[j]) + bf2f((u16)v2[j]) + pv[j];
        f[j] = s > 0.f ? s : 0.f;
      }
      uint4 ov;
      ov.x = pk2(f[0],f[1]); ov.y = pk2(f[2],f[3]);
      ov.z = pk2(f[4],f[5]); ov.w = pk2(f[6],f[7]);
      *(uint4*)(t_lds + rstage*264 + c0) = ov;
    }
  }

  const u16* w2p = w2t + ((size_t)layer*256 + tid)*256;
  f32x4 acc[4][4];
  for (int mi = 0; mi < 4; ++mi)
    for (int nj = 0; nj < 4; ++nj)
      acc[mi][nj] = (f32x4){0.f,0.f,0.f,0.f};

  // ---- GEMM2: [64x256] @ [256x256] ----
  for (int ks = 0; ks < 8; ++ks){
    __syncthreads();
    {
      const u16* src = w2p + ks*32;
      uint4 s0 = *(const uint4*)(src);
      uint4 s1 = *(const uint4*)(src + 8);
      uint4 s2 = *(const uint4*)(src + 16);
      uint4 s3 = *(const uint4*)(src + 24);
      u16* dst = b_lds + tid*40;
      *(uint4*)(dst)      = s0;
      *(uint4*)(dst + 8)  = s1;
      *(uint4*)(dst + 16) = s2;
      *(uint4*)(dst + 24) = s3;
    }
    __syncthreads();
    bf16x8 af[4], bfr[4];
    for (int mi = 0; mi < 4; ++mi)
      af[mi] = *(const bf16x8*)(t_lds + (mi*16 + lr)*264 + ks*32 + g*8);
    for (int nj = 0; nj < 4; ++nj)
      bfr[nj] = *(const bf16x8*)(b_lds + (w*64 + nj*16 + lr)*40 + g*8);
    for (int mi = 0; mi < 4; ++mi)
      for (int nj = 0; nj < 4; ++nj)
        acc[mi][nj] = __builtin_amdgcn_mfma_f32_16x16x32_bf16(af[mi], bfr[nj], acc[mi][nj], 0, 0, 0);
  }

  __syncthreads();
  // ---- epilogue: (+b2)*gate -> bf16 msgs transposed [col][edge] ----
  {
    float b2v[4];
    for (int nj = 0; nj < 4; ++nj) b2v[nj] = b2g[layer*HD + w*64 + nj*16 + lr];
    for (int mi = 0; mi < 4; ++mi)
      for (int nj = 0; nj < 4; ++nj){
        int colt = w*64 + nj*16 + lr;
        for (int p = 0; p < 4; ++p){
          int re = mi*16 + g*4 + p;
          float val = (acc[mi][nj][p] + b2v[nj]) * gate_l[re];
          t_lds[colt*72 + re] = f2bf(val);
        }
      }
  }
  __syncthreads();

  // ---- segmented reduction over sorted rows, atomics per (row,col) run ----
  {
    const int c = tid;
    float run = 0.f;
    int currow = row_l[0];
    for (int it = 0; it < 8; ++it){
      bf16x8 mv = *(const bf16x8*)(t_lds + c*72 + it*8);
      #pragma unroll
      for (int j = 0; j < 8; ++j){
        int r = row_l[it*8 + j];
        if (r != currow){
          atomicAdd(h + (size_t)currow*HD + c, run);
          run = 0.f; currow = r;
        }
        run += bf2f((u16)mv[j]);
      }
    }
    atomicAdd(h + (size_t)currow*HD + c, run);
  }
}

// ---- column sums for pooling ----
__global__ void pool_k(const float* __restrict__ h,
                       float* __restrict__ pooled){
  int c = threadIdx.x;
  int r0 = blockIdx.x * 250;
  float s = 0.f;
  for (int r = r0; r < r0 + 250; ++r)
    s += h[(size_t)r*HD + c];
  atomicAdd(&pooled[c], s);
}

__global__ void fg_k(const float* __restrict__ pooled,
                     const float* __restrict__ fg_w,
                     const float* __restrict__ fg_b,
                     float* __restrict__ fg_vals){
  int o = threadIdx.x;
  int k = o >> 4, j = o & 15;
  float s = 0.f;
  for (int d = 0; d < HD; ++d) s += pooled[d] * fg_w[(size_t)k*HD*16 + d*16 + j];
  fg_vals[o] = s / (float)NN + fg_b[k*16 + j];
}

__global__ void bcast_fg_k(const float* __restrict__ fg_vals,
                           float* __restrict__ out_fg){
  __shared__ float fv[64];
  if (threadIdx.x < 64) fv[threadIdx.x] = fg_vals[threadIdx.x];
  __syncthreads();
  int i = blockIdx.x*256 + threadIdx.x;
  out_fg[i] = fv[i & 63];
}

__global__ void props_k(const float* __restrict__ h,
                        const float* __restrict__ w1,
                        const float* __restrict__ b1,
                        const float* __restrict__ w2,
                        const float* __restrict__ b2,
                        float* __restrict__ outp){
  __shared__ float hrow[256];
  __shared__ float tbuf[128];
  int n = blockIdx.x, c = threadIdx.x;
  hrow[c]       = h[(size_t)n*HD + c];
  hrow[c + 128] = h[(size_t)n*HD + 128 + c];
  __syncthreads();
  float s = b1[c];
  for (int d = 0; d < 256; ++d) s += hrow[d] * w1[d*128 + c];
  tbuf[c] = s > 0.f ? s : 0.f;
  __syncthreads();
  if (c < 32){
    float s2 = b2[c];
    for (int d = 0; d < 128; ++d) s2 += tbuf[d] * w2[d*32 + c];
    outp[(size_t)n*32 + c] = s2;
  }
}

extern "C" void kernel_launch(void* const* d_in, const int* in_sizes, int n_in,
                              void* d_out, int out_size, void* d_ws, size_t ws_size,
                              hipStream_t stream) {
  const float* x            = (const float*)d_in[0];
  const int*   eidx         = (const int*)  d_in[1];
  const float* eattr        = (const float*)d_in[2];
  const float* atom_table   = (const float*)d_in[4];
  const float* charge_table = (const float*)d_in[5];
  const float* hybrid_table = (const float*)d_in[6];
  const float* bond_table   = (const float*)d_in[7];
  const float* gw1          = (const float*)d_in[8];
  const float* gb1          = (const float*)d_in[9];
  const float* gw2          = (const float*)d_in[10];
  const float* gb2          = (const float*)d_in[11];
  const float* attw         = (const float*)d_in[12];
  const float* attb         = (const float*)d_in[13];
  const float* pw1          = (const float*)d_in[14];
  const float* pb1          = (const float*)d_in[15];
  const float* pw2          = (const float*)d_in[16];
  const float* pb2          = (const float*)d_in[17];
  const float* fgw          = (const float*)d_in[18];
  const float* fgb          = (const float*)d_in[19];

  float* out       = (float*)d_out;
  float* out_h     = out;                          // h lives here (in-place update)
  float* out_props = out + (size_t)NN*HD;
  float* out_fg    = out_props + (size_t)NN*32;
  float* out_at    = out_fg + (size_t)NN*64;

  char* ws = (char*)d_ws;
  u16*   pre      = (u16*)  (ws + WS_PRE);
  u16*   w1t      = (u16*)  (ws + WS_W1T);
  u16*   w2t      = (u16*)  (ws + WS_W2T);
  float* prebg    = (float*)(ws + WS_PREB);
  float* gate_tab = (float*)(ws + WS_GATE);
  float* pooled   = (float*)(ws + WS_POOL);
  float* fg_vals  = (float*)(ws + WS_FGV);
  int*   cnt      = (int*)  (ws + WS_CNT);
  int*   eord     = (int*)  (ws + WS_EORD);

  conv_w1ab_k<<<1536, 256, 0, stream>>>(gw1, w1t);
  conv_w2_k<<<768, 256, 0, stream>>>(gw2, w2t);
  preb_k<<<3, 256, 0, stream>>>(bond_table, gw1, gb1, prebg);
  gate_zero_k<<<1, 64, 0, stream>>>(bond_table, attw, attb, gate_tab, pooled);
  zero_counts_k<<<79, 256, 0, stream>>>(cnt);
  init_embed_k<<<NN, 256, 0, stream>>>(x, atom_table, charge_table, hybrid_table, out_h, out_at);

  hist_k<<<1250, 256, 0, stream>>>(eidx, cnt);
  scan_k<<<1, 1024, 0, stream>>>(cnt);
  scatter_k<<<1250, 256, 0, stream>>>(eidx, cnt, eord);

  for (int l = 0; l < 3; ++l){
    pre_k<<<dim3(313, 2), 256, 0, stream>>>(out_h, w1t, pre, l);
    edge_msg_k<<<5000, 256, 0, stream>>>(eidx, eattr, eord, pre, prebg, w2t,
                                         gb2, gate_tab, out_h, l);
  }

  pool_k<<<80, 256, 0, stream>>>(out_h, pooled);
  fg_k<<<1, 64, 0, stream>>>(pooled, fgw, fgb, fg_vals);
  bcast_fg_k<<<5000, 256, 0, stream>>>(fg_vals, out_fg);
  props_k<<<NN, 128, 0, stream>>>(out_h, pw1, pb1, pw2, pb2, out_props);
}

// Round 4
// 684.201 us; speedup vs baseline: 2.3249x; 1.1563x over previous
//
#include <hip/hip_runtime.h>
#include <stdint.h>

typedef unsigned short u16;
typedef unsigned int   u32;
typedef __attribute__((ext_vector_type(8))) short bf16x8;
typedef __attribute__((ext_vector_type(4))) float f32x4;

#define NN 20000
#define NE 320000
#define HD 256
#define BD 64

// ws layout (bytes) — total ~23.1 MB
#define WS_PRE   0u           // bf16 [NN][512]  (pre1|pre2)   20,480,000
#define WS_W1T   20480000u    // bf16 [3][512][256]               786,432
#define WS_W2I   21266432u    // bf16 W2 swizzled image           393,216
#define WS_PREB  21659648u    // f32  [3][5][256]                  15,360
#define WS_GATE  21675008u    // f32  [15]
#define WS_POOL  21675072u    // f32  [256]
#define WS_FGV   21676096u    // f32  [64]
#define WS_CNT   21676352u    // int  [NN]                         80,000
#define WS_EORD  21756352u    // int  [NE]                      1,280,000
#define WS_PW1   23036352u    // bf16 [128][256] props W1^T        65,536

__device__ __forceinline__ u16 f2bf(float f){
  u32 u = __float_as_uint(f);
  u += 0x7fffu + ((u >> 16) & 1u);
  return (u16)(u >> 16);
}
__device__ __forceinline__ u32 pk2(float a, float b){
  return (u32)f2bf(a) | ((u32)f2bf(b) << 16);
}
__device__ __forceinline__ float bf2f(u16 u){
  return __uint_as_float((u32)u << 16);
}
__device__ __forceinline__ void gl_lds16(const u16* g, u16* l){
  __builtin_amdgcn_global_load_lds(
      (const __attribute__((address_space(1))) unsigned int*)g,
      (__attribute__((address_space(3))) unsigned int*)l, 16, 0, 0);
}

// ---- W1[0:512] -> bf16 transposed [3][512][256 k] ----
__global__ void conv_w1ab_k(const float* __restrict__ w, u16* __restrict__ wt){
  int i = blockIdx.x*256 + threadIdx.x;
  if (i >= 3*512*256) return;
  int l = i >> 17;
  int r = i & 131071;
  int c = r >> 8;
  int k = r & 255;
  int srow = (c < 256) ? k : (256 + k);
  wt[i] = f2bf(w[(l*576 + srow)*256 + (c & 255)]);
}

// ---- W2 -> swizzled bf16 image for global_load_lds staging ----
// img[(((l*8+ks)*256 + c)*4 + s)*8 + j] = W2[k][c], k = ks*32 + (s^((c>>1)&3))*8 + j
__global__ void conv_w2img_k(const float* __restrict__ w, u16* __restrict__ img){
  int i = blockIdx.x*256 + threadIdx.x;
  if (i >= 3*8*256*4*8) return;
  int j  = i & 7;
  int s  = (i >> 3) & 3;
  int c  = (i >> 5) & 255;
  int ks = (i >> 13) & 7;
  int l  = i >> 16;
  int kc = s ^ ((c >> 1) & 3);
  int k  = ks*32 + kc*8 + j;
  img[i] = f2bf(w[(l*256 + k)*256 + c]);
}

// ---- props W1 [256][128] -> bf16 [128 out][256 k] ----
__global__ void conv_pw1_k(const float* __restrict__ w, u16* __restrict__ wt){
  int i = blockIdx.x*256 + threadIdx.x;
  if (i >= 128*256) return;
  int o = i >> 8, k = i & 255;
  wt[i] = f2bf(w[k*128 + o]);
}

// ---- preb[l][bt][c] = b1[l][c] + bond[bt] @ W1[512:576] ----
__global__ void preb_k(const float* __restrict__ bond_table,
                       const float* __restrict__ gw1,
                       const float* __restrict__ gb1,
                       float* __restrict__ preb){
  int l = blockIdx.x, c = threadIdx.x;
  for (int bt = 0; bt < 5; ++bt){
    float s = gb1[l*HD + c];
    for (int d = 0; d < BD; ++d)
      s += bond_table[bt*BD + d] * gw1[(l*576 + 512 + d)*256 + c];
    preb[(l*5 + bt)*256 + c] = s;
  }
}

__global__ void gate_zero_k(const float* __restrict__ bond_table,
                            const float* __restrict__ att_w,
                            const float* __restrict__ att_b,
                            float* __restrict__ gate_tab,
                            float* __restrict__ pooled){
  int t = threadIdx.x;
  if (t < 15){
    int l = t / 5, b = t - 5*l;
    float s = att_b[l];
    for (int d = 0; d < BD; ++d) s += bond_table[b*BD + d] * att_w[l*BD + d];
    gate_tab[t] = 1.0f / (1.0f + __expf(-s));
  }
  for (int i = t; i < HD; i += 64) pooled[i] = 0.0f;
}

__global__ void zero_counts_k(int* __restrict__ cnt){
  int i = blockIdx.x*256 + threadIdx.x;
  if (i < NN) cnt[i] = 0;
}

__global__ void init_embed_k(const float* __restrict__ x,
                             const float* __restrict__ atom_table,
                             const float* __restrict__ charge_table,
                             const float* __restrict__ hybrid_table,
                             float* __restrict__ h0,
                             float* __restrict__ out_at){
  int n = blockIdx.x, c = threadIdx.x;
  int at = (int)x[n*3 + 0]; at = at < 0 ? 0 : (at > 10 ? 10 : at);
  int hy = (int)x[n*3 + 1]; hy = hy < 0 ? 0 : (hy > 7 ? 7 : hy);
  int fc = (int)x[n*3 + 2] + 3; fc = fc < 0 ? 0 : (fc > 6 ? 6 : fc);
  float v = 0.0f;
  if (c < 64)       v = atom_table[at*64 + c];
  else if (c < 96)  v = charge_table[fc*32 + (c - 64)];
  else if (c < 128) v = hybrid_table[hy*32 + (c - 96)];
  h0[(size_t)n*HD + c] = v;
  if (c == 0) out_at[n] = (float)at;
}

// ---- counting sort by row ----
__global__ void hist_k(const int* __restrict__ eidx, int* __restrict__ cnt){
  int e = blockIdx.x*256 + threadIdx.x;
  int r = eidx[e]; r = r < 0 ? 0 : (r >= NN ? NN-1 : r);
  atomicAdd(&cnt[r], 1);
}

__launch_bounds__(1024)
__global__ void scan_k(int* __restrict__ cnt){
  __shared__ int part[1024];
  int t = threadIdx.x;
  int base = t*20;
  int loc[20];
  int s = 0;
  #pragma unroll
  for (int j = 0; j < 20; ++j){
    int idx = base + j;
    int v = (idx < NN) ? cnt[idx] : 0;
    loc[j] = v; s += v;
  }
  part[t] = s; __syncthreads();
  for (int off = 1; off < 1024; off <<= 1){
    int v = (t >= off) ? part[t-off] : 0;
    __syncthreads();
    part[t] += v;
    __syncthreads();
  }
  int run = part[t] - s;
  #pragma unroll
  for (int j = 0; j < 20; ++j){
    int idx = base + j;
    if (idx < NN){ cnt[idx] = run; run += loc[j]; }
  }
}

__global__ void scatter_k(const int* __restrict__ eidx, int* __restrict__ cur,
                          int* __restrict__ eord){
  int e = blockIdx.x*256 + threadIdx.x;
  int r = eidx[e]; r = r < 0 ? 0 : (r >= NN ? NN-1 : r);
  int pos = atomicAdd(&cur[r], 1);
  if (pos >= 0 && pos < NE) eord[pos] = e;
}

// ---- pre = bf16( h @ [W1a|W1b] ) : [NN][512] ----
__launch_bounds__(256, 2)
__global__ void pre_k(const float* __restrict__ h,
                      const u16* __restrict__ w1t,
                      u16* __restrict__ pre, int layer){
  __shared__ u16 a_lds[64*40];
  __shared__ u16 b_lds[256*40];
  const int tid = threadIdx.x;
  const int n0 = blockIdx.x * 64;
  const int half = blockIdx.y;
  const int w = tid >> 6, lane = tid & 63, g = lane >> 4, lr = lane & 15;
  const int rstage = tid >> 2, q = tid & 3;
  int arow = n0 + rstage; if (arow >= NN) arow = NN-1;
  const float* hrow = h + (size_t)arow*HD;
  const u16* bp = w1t + ((size_t)layer*512 + (size_t)half*256 + tid)*256;

  f32x4 acc[4][4];
  for (int mi = 0; mi < 4; ++mi)
    for (int nj = 0; nj < 4; ++nj)
      acc[mi][nj] = (f32x4){0.f,0.f,0.f,0.f};

  for (int ks = 0; ks < 8; ++ks){
    __syncthreads();
    {
      const float* src = hrow + ks*32 + q*8;
      float4 f0 = *(const float4*)src;
      float4 f1 = *(const float4*)(src + 4);
      uint4 av;
      av.x = pk2(f0.x,f0.y); av.y = pk2(f0.z,f0.w);
      av.z = pk2(f1.x,f1.y); av.w = pk2(f1.z,f1.w);
      *(uint4*)(a_lds + rstage*40 + q*8) = av;
    }
    {
      const u16* src = bp + ks*32;
      uint4 s0 = *(const uint4*)(src);
      uint4 s1 = *(const uint4*)(src + 8);
      uint4 s2 = *(const uint4*)(src + 16);
      uint4 s3 = *(const uint4*)(src + 24);
      u16* dst = b_lds + tid*40;
      *(uint4*)(dst)      = s0;
      *(uint4*)(dst + 8)  = s1;
      *(uint4*)(dst + 16) = s2;
      *(uint4*)(dst + 24) = s3;
    }
    __syncthreads();
    bf16x8 af[4], bfr[4];
    for (int mi = 0; mi < 4; ++mi)
      af[mi] = *(const bf16x8*)(a_lds + (mi*16 + lr)*40 + g*8);
    for (int nj = 0; nj < 4; ++nj)
      bfr[nj] = *(const bf16x8*)(b_lds + (w*64 + nj*16 + lr)*40 + g*8);
    for (int mi = 0; mi < 4; ++mi)
      for (int nj = 0; nj < 4; ++nj)
        acc[mi][nj] = __builtin_amdgcn_mfma_f32_16x16x32_bf16(af[mi], bfr[nj], acc[mi][nj], 0, 0, 0);
  }

  for (int mi = 0; mi < 4; ++mi)
    for (int nj = 0; nj < 4; ++nj)
      for (int p = 0; p < 4; ++p){
        int re = mi*16 + g*4 + p;
        int n = n0 + re;
        if (n < NN)
          pre[(size_t)n*512 + half*256 + w*64 + nj*16 + lr] = f2bf(acc[mi][nj][p]);
      }
}

// ---- fused edge kernel: ONE barrier, wave-private pipelined GEMM2 ----
__launch_bounds__(256, 2)
__global__ void edge_msg_k(const int* __restrict__ eidx,
                           const float* __restrict__ eattr,
                           const int* __restrict__ eord,
                           const u16* __restrict__ pre,
                           const float* __restrict__ prebg,
                           const u16* __restrict__ w2img,
                           const float* __restrict__ b2g,
                           const float* __restrict__ gate_tab,
                           float* __restrict__ h,
                           int layer){
  __shared__ u16 b_lds[16384];     // 32KB: 2 bufs x (256 cols x 32k) swizzled; reused for msgs
  __shared__ u16 t_lds[64*264];    // 33792B
  __shared__ int   row_l[64];
  __shared__ float gate_l[64];

  const int tid = threadIdx.x;
  const int eBase = blockIdx.x * 64;
  const int w = tid >> 6, lane = tid & 63, g = lane >> 4, lr = lane & 15;
  const int rstage = tid >> 2, q = tid & 3;

  const size_t wbase = (size_t)layer*65536;

  // prefetch W2 k-step 0 into buf0 (wave-private slice)
  #pragma unroll
  for (int j4 = 0; j4 < 4; ++j4)
    gl_lds16(w2img + wbase + (size_t)(w*64 + j4*16)*32 + lane*8,
             b_lds + w*2048 + j4*512);

  // per-thread edge metadata (clamped)
  int e0 = eord[eBase + rstage]; e0 = e0 < 0 ? 0 : (e0 >= NE ? NE-1 : e0);
  int rI  = eidx[e0];       rI  = rI  < 0 ? 0 : (rI  >= NN ? NN-1 : rI);
  int cI  = eidx[NE + e0];  cI  = cI  < 0 ? 0 : (cI  >= NN ? NN-1 : cI);
  int btI = (int)eattr[e0]; btI = btI < 0 ? 0 : (btI > 4 ? 4 : btI);

  if (tid < 64){
    int e = eord[eBase + tid]; e = e < 0 ? 0 : (e >= NE ? NE-1 : e);
    int r  = eidx[e];       r  = r  < 0 ? 0 : (r >= NN ? NN-1 : r);
    int bt = (int)eattr[e]; bt = bt < 0 ? 0 : (bt > 4 ? 4 : bt);
    row_l[tid]  = r;
    gate_l[tid] = gate_tab[layer*5 + bt];
  }

  // ---- t = relu(pre1[row] + pre2[col] + preb[bt]) -> bf16 t_lds ----
  {
    const u16* p1 = pre + (size_t)rI*512;
    const u16* p2 = pre + (size_t)cI*512 + 256;
    const float* pb = prebg + (size_t)(layer*5 + btI)*256;
    for (int it = 0; it < 8; ++it){
      int c0 = q*64 + it*8;
      bf16x8 v1 = *(const bf16x8*)(p1 + c0);
      bf16x8 v2 = *(const bf16x8*)(p2 + c0);
      float pv[8];
      *(float4*)(pv)     = *(const float4*)(pb + c0);
      *(float4*)(pv + 4) = *(const float4*)(pb + c0 + 4);
      float f[8];
      #pragma unroll
      for (int j = 0; j < 8; ++j){
        float s = bf2f((u16)v1[j]) + bf2f((u16)v2[j]) + pv[j];
        f[j] = s > 0.f ? s : 0.f;
      }
      uint4 ov;
      ov.x = pk2(f[0],f[1]); ov.y = pk2(f[2],f[3]);
      ov.z = pk2(f[4],f[5]); ov.w = pk2(f[6],f[7]);
      *(uint4*)(t_lds + rstage*264 + c0) = ov;
    }
  }

  // prefetch W2 k-step 1 into buf1
  #pragma unroll
  for (int j4 = 0; j4 < 4; ++j4)
    gl_lds16(w2img + wbase + 8192 + (size_t)(w*64 + j4*16)*32 + lane*8,
             b_lds + 8192 + w*2048 + j4*512);

  __syncthreads();   // the ONLY barrier: t_lds + row_l/gate_l visible

  f32x4 acc[4][4];
  for (int mi = 0; mi < 4; ++mi)
    for (int nj = 0; nj < 4; ++nj)
      acc[mi][nj] = (f32x4){0.f,0.f,0.f,0.f};

  const int sw = (g ^ ((lr >> 1) & 3)) << 3;

  // ---- GEMM2: barrier-free, wave-private double-buffered W2 staging ----
  #pragma unroll
  for (int ks = 0; ks < 8; ++ks){
    if (ks < 7){
      const size_t kb = wbase + (size_t)(ks+1)*8192;
      #pragma unroll
      for (int j4 = 0; j4 < 4; ++j4)
        gl_lds16(w2img + kb + (size_t)(w*64 + j4*16)*32 + lane*8,
                 b_lds + ((ks+1)&1)*8192 + w*2048 + j4*512);
      asm volatile("s_waitcnt vmcnt(4)" ::: "memory");
    } else {
      asm volatile("s_waitcnt vmcnt(0)" ::: "memory");
    }
    bf16x8 af[4], bfr[4];
    const u16* bb = b_lds + (ks&1)*8192;
    for (int nj = 0; nj < 4; ++nj)
      bfr[nj] = *(const bf16x8*)(bb + (w*64 + nj*16 + lr)*32 + sw);
    for (int mi = 0; mi < 4; ++mi)
      af[mi] = *(const bf16x8*)(t_lds + (mi*16 + lr)*264 + ks*32 + g*8);
    __builtin_amdgcn_s_setprio(1);
    for (int mi = 0; mi < 4; ++mi)
      for (int nj = 0; nj < 4; ++nj)
        acc[mi][nj] = __builtin_amdgcn_mfma_f32_16x16x32_bf16(af[mi], bfr[nj], acc[mi][nj], 0, 0, 0);
    __builtin_amdgcn_s_setprio(0);
  }

  // ---- epilogue: (+b2)*gate -> bf16 msgs in wave-private b_lds slices ----
  {
    float b2v[4];
    for (int nj = 0; nj < 4; ++nj) b2v[nj] = b2g[layer*HD + w*64 + nj*16 + lr];
    for (int mi = 0; mi < 4; ++mi)
      for (int nj = 0; nj < 4; ++nj){
        int cl = nj*16 + lr;
        u16* mb = b_lds + (cl >> 5)*8192 + w*2048 + (cl & 31)*64;
        for (int p = 0; p < 4; ++p){
          int re = mi*16 + g*4 + p;
          float val = (acc[mi][nj][p] + b2v[nj]) * gate_l[re];
          mb[(((re >> 3) ^ (cl & 7)) << 3) + (re & 7)] = f2bf(val);
        }
      }
  }

  // ---- segmented reduction over sorted rows (wave-local msgs) ----
  {
    const int cl = tid & 63;
    const u16* mb = b_lds + (cl >> 5)*8192 + w*2048 + (cl & 31)*64;
    float run = 0.f;
    int currow = row_l[0];
    for (int it = 0; it < 8; ++it){
      bf16x8 mv = *(const bf16x8*)(mb + ((it ^ (cl & 7)) << 3));
      #pragma unroll
      for (int j = 0; j < 8; ++j){
        int r = row_l[it*8 + j];
        if (r != currow){
          atomicAdd(h + (size_t)currow*HD + tid, run);
          run = 0.f; currow = r;
        }
        run += bf2f((u16)mv[j]);
      }
    }
    atomicAdd(h + (size_t)currow*HD + tid, run);
  }
}

// ---- column sums for pooling ----
__global__ void pool_k(const float* __restrict__ h,
                       float* __restrict__ pooled){
  int c = threadIdx.x;
  int r0 = blockIdx.x * 250;
  float s = 0.f;
  for (int r = r0; r < r0 + 250; ++r)
    s += h[(size_t)r*HD + c];
  atomicAdd(&pooled[c], s);
}

__global__ void fg_k(const float* __restrict__ pooled,
                     const float* __restrict__ fg_w,
                     const float* __restrict__ fg_b,
                     float* __restrict__ fg_vals){
  int o = threadIdx.x;
  int k = o >> 4, j = o & 15;
  float s = 0.f;
  for (int d = 0; d < HD; ++d) s += pooled[d] * fg_w[(size_t)k*HD*16 + d*16 + j];
  fg_vals[o] = s / (float)NN + fg_b[k*16 + j];
}

__global__ void bcast_fg_k(const float* __restrict__ fg_vals,
                           float* __restrict__ out_fg){
  __shared__ float fv[64];
  if (threadIdx.x < 64) fv[threadIdx.x] = fg_vals[threadIdx.x];
  __syncthreads();
  int i = blockIdx.x*256 + threadIdx.x;
  out_fg[i] = fv[i & 63];
}

// ---- chemical properties MLP via MFMA ----
__launch_bounds__(256, 2)
__global__ void props_mfma_k(const float* __restrict__ h,
                             const u16* __restrict__ pw1bf,
                             const float* __restrict__ pb1,
                             const float* __restrict__ pw2,
                             const float* __restrict__ pb2,
                             float* __restrict__ outp){
  __shared__ u16 a_lds[64*40];
  __shared__ u16 b2_lds[128*40];
  __shared__ u16 t2[64*136];
  __shared__ float w2s[128*32];
  const int tid = threadIdx.x;
  const int n0 = blockIdx.x*64;
  const int w = tid >> 6, lane = tid & 63, g = lane >> 4, lr = lane & 15;
  const int rstage = tid >> 2, q = tid & 3;
  int arow = n0 + rstage; if (arow >= NN) arow = NN-1;
  const float* hrow = h + (size_t)arow*HD;

  // preload pw2 fp32 into LDS
  for (int j = 0; j < 4; ++j)
    *(float4*)(w2s + tid*16 + j*4) = *(const float4*)(pw2 + tid*16 + j*4);

  const int colb = tid >> 1, halfb = tid & 1;

  f32x4 acc[4][2];
  for (int mi = 0; mi < 4; ++mi)
    for (int nj = 0; nj < 2; ++nj)
      acc[mi][nj] = (f32x4){0.f,0.f,0.f,0.f};

  for (int ks = 0; ks < 8; ++ks){
    __syncthreads();
    {
      const float* src = hrow + ks*32 + q*8;
      float4 f0 = *(const float4*)src;
      float4 f1 = *(const float4*)(src + 4);
      uint4 av;
      av.x = pk2(f0.x,f0.y); av.y = pk2(f0.z,f0.w);
      av.z = pk2(f1.x,f1.y); av.w = pk2(f1.z,f1.w);
      *(uint4*)(a_lds + rstage*40 + q*8) = av;
    }
    {
      const u16* src = pw1bf + colb*256 + ks*32 + halfb*16;
      uint4 s0 = *(const uint4*)src;
      uint4 s1 = *(const uint4*)(src + 8);
      u16* dst = b2_lds + colb*40 + halfb*16;
      *(uint4*)dst = s0; *(uint4*)(dst + 8) = s1;
    }
    __syncthreads();
    bf16x8 af[4], bfr[2];
    for (int mi = 0; mi < 4; ++mi)
      af[mi] = *(const bf16x8*)(a_lds + (mi*16 + lr)*40 + g*8);
    for (int nj = 0; nj < 2; ++nj)
      bfr[nj] = *(const bf16x8*)(b2_lds + (w*32 + nj*16 + lr)*40 + g*8);
    for (int mi = 0; mi < 4; ++mi)
      for (int nj = 0; nj < 2; ++nj)
        acc[mi][nj] = __builtin_amdgcn_mfma_f32_16x16x32_bf16(af[mi], bfr[nj], acc[mi][nj], 0, 0, 0);
  }

  // bias + relu -> t2
  {
    float b1v[2];
    for (int nj = 0; nj < 2; ++nj) b1v[nj] = pb1[w*32 + nj*16 + lr];
    for (int mi = 0; mi < 4; ++mi)
      for (int nj = 0; nj < 2; ++nj){
        int colt = w*32 + nj*16 + lr;
        for (int p = 0; p < 4; ++p){
          float v = acc[mi][nj][p] + b1v[nj];
          v = v > 0.f ? v : 0.f;
          t2[(mi*16 + g*4 + p)*136 + colt] = f2bf(v);
        }
      }
  }
  __syncthreads();

  // phase 2: out[e][o0..o0+7] = pb2 + t2[e]@pw2
  {
    int e = tid >> 2, o0 = (tid & 3)*8;
    int n = n0 + e;
    float ap[8];
    #pragma unroll
    for (int o = 0; o < 8; ++o) ap[o] = pb2[o0 + o];
    for (int d0 = 0; d0 < 16; ++d0){
      bf16x8 tv = *(const bf16x8*)(t2 + e*136 + d0*8);
      #pragma unroll
      for (int dd = 0; dd < 8; ++dd){
        float t = bf2f((u16)tv[dd]);
        const float* wr = w2s + (d0*8 + dd)*32 + o0;
        #pragma unroll
        for (int o = 0; o < 8; ++o) ap[o] += t * wr[o];
      }
    }
    if (n < NN){
      *(float4*)(outp + (size_t)n*32 + o0)     = *(float4*)(ap);
      *(float4*)(outp + (size_t)n*32 + o0 + 4) = *(float4*)(ap + 4);
    }
  }
}

extern "C" void kernel_launch(void* const* d_in, const int* in_sizes, int n_in,
                              void* d_out, int out_size, void* d_ws, size_t ws_size,
                              hipStream_t stream) {
  const float* x            = (const float*)d_in[0];
  const int*   eidx         = (const int*)  d_in[1];
  const float* eattr        = (const float*)d_in[2];
  const float* atom_table   = (const float*)d_in[4];
  const float* charge_table = (const float*)d_in[5];
  const float* hybrid_table = (const float*)d_in[6];
  const float* bond_table   = (const float*)d_in[7];
  const float* gw1          = (const float*)d_in[8];
  const float* gb1          = (const float*)d_in[9];
  const float* gw2          = (const float*)d_in[10];
  const float* gb2          = (const float*)d_in[11];
  const float* attw         = (const float*)d_in[12];
  const float* attb         = (const float*)d_in[13];
  const float* pw1          = (const float*)d_in[14];
  const float* pb1          = (const float*)d_in[15];
  const float* pw2          = (const float*)d_in[16];
  const float* pb2          = (const float*)d_in[17];
  const float* fgw          = (const float*)d_in[18];
  const float* fgb          = (const float*)d_in[19];

  float* out       = (float*)d_out;
  float* out_h     = out;
  float* out_props = out + (size_t)NN*HD;
  float* out_fg    = out_props + (size_t)NN*32;
  float* out_at    = out_fg + (size_t)NN*64;

  char* ws = (char*)d_ws;
  u16*   pre      = (u16*)  (ws + WS_PRE);
  u16*   w1t      = (u16*)  (ws + WS_W1T);
  u16*   w2img    = (u16*)  (ws + WS_W2I);
  float* prebg    = (float*)(ws + WS_PREB);
  float* gate_tab = (float*)(ws + WS_GATE);
  float* pooled   = (float*)(ws + WS_POOL);
  float* fg_vals  = (float*)(ws + WS_FGV);
  int*   cnt      = (int*)  (ws + WS_CNT);
  int*   eord     = (int*)  (ws + WS_EORD);
  u16*   pw1bf    = (u16*)  (ws + WS_PW1);

  conv_w1ab_k<<<1536, 256, 0, stream>>>(gw1, w1t);
  conv_w2img_k<<<768, 256, 0, stream>>>(gw2, w2img);
  conv_pw1_k<<<128, 256, 0, stream>>>(pw1, pw1bf);
  preb_k<<<3, 256, 0, stream>>>(bond_table, gw1, gb1, prebg);
  gate_zero_k<<<1, 64, 0, stream>>>(bond_table, attw, attb, gate_tab, pooled);
  zero_counts_k<<<79, 256, 0, stream>>>(cnt);
  init_embed_k<<<NN, 256, 0, stream>>>(x, atom_table, charge_table, hybrid_table, out_h, out_at);

  hist_k<<<1250, 256, 0, stream>>>(eidx, cnt);
  scan_k<<<1, 1024, 0, stream>>>(cnt);
  scatter_k<<<1250, 256, 0, stream>>>(eidx, cnt, eord);

  for (int l = 0; l < 3; ++l){
    pre_k<<<dim3(313, 2), 256, 0, stream>>>(out_h, w1t, pre, l);
    edge_msg_k<<<5000, 256, 0, stream>>>(eidx, eattr, eord, pre, prebg, w2img,
                                         gb2, gate_tab, out_h, l);
  }

  pool_k<<<80, 256, 0, stream>>>(out_h, pooled);
  fg_k<<<1, 64, 0, stream>>>(pooled, fgw, fgb, fg_vals);
  bcast_fg_k<<<5000, 256, 0, stream>>>(fg_vals, out_fg);
  props_mfma_k<<<313, 256, 0, stream>>>(out_h, pw1bf, pb1, pw2, pb2, out_props);
}

// Round 5
// 423.868 us; speedup vs baseline: 3.7529x; 1.6142x over previous
//
#include <hip/hip_runtime.h>
#include <stdint.h>

typedef unsigned short u16;
typedef unsigned int   u32;
typedef __attribute__((ext_vector_type(8))) short bf16x8;
typedef __attribute__((ext_vector_type(4))) float f32x4;

#define NN 20000
#define NE 320000
#define HD 256
#define BD 64

// ws layout (bytes) — total ~24.4 MB
#define WS_PRE   0u           // bf16 [NN][512]                20,480,000
#define WS_W1T   20480000u    // bf16 [3][512][256]               786,432
#define WS_W2I   21266432u    // bf16 W2 swizzled image           393,216
#define WS_PW1   21659648u    // bf16 [128][256]                   65,536
#define WS_PREB  21725184u    // f32  [3][5][256]                  15,360
#define WS_GATE  21740544u    // f32  [15]
#define WS_POOL  21740608u    // f32  [256]
#define WS_FGV   21741632u    // f32  [64]
#define WS_CNT   21741888u    // int  [NN]                         80,000
#define WS_META  21821888u    // int2 [NE] sorted {row|bt<<20,col} 2,560,000

__device__ __forceinline__ u16 f2bf(float f){
  u32 u = __float_as_uint(f);
  u += 0x7fffu + ((u >> 16) & 1u);
  return (u16)(u >> 16);
}
__device__ __forceinline__ u32 pk2(float a, float b){
  return (u32)f2bf(a) | ((u32)f2bf(b) << 16);
}
__device__ __forceinline__ float bf2f(u16 u){
  return __uint_as_float((u32)u << 16);
}
__device__ __forceinline__ void gl_lds16(const u16* g, u16* l){
  __builtin_amdgcn_global_load_lds(
      (const __attribute__((address_space(1))) unsigned int*)g,
      (__attribute__((address_space(3))) unsigned int*)l, 16, 0, 0);
}

// ---- merged one-time setup: weight images + preb + gate + zeros ----
// ranges: [0,393216) w1t | [393216,589824) w2img | [589824,622592) pw1
//         [622592,626432) preb | [626432,626447) gate | [626447,626703) pooled
//         [626703,646703) cnt
__global__ void setup_k(const float* __restrict__ gw1,
                        const float* __restrict__ gw2,
                        const float* __restrict__ pw1,
                        const float* __restrict__ bond_table,
                        const float* __restrict__ gb1,
                        const float* __restrict__ att_w,
                        const float* __restrict__ att_b,
                        u16* __restrict__ w1t, u16* __restrict__ w2img,
                        u16* __restrict__ pw1bf, float* __restrict__ preb,
                        float* __restrict__ gate_tab, float* __restrict__ pooled,
                        int* __restrict__ cnt){
  int i = blockIdx.x*256 + threadIdx.x;
  if (i < 393216){
    int l = i >> 17;
    int r = i & 131071;
    int c = r >> 8;
    int k = r & 255;
    int srow = (c < 256) ? k : (256 + k);
    w1t[i] = f2bf(gw1[(l*576 + srow)*256 + (c & 255)]);
  } else if (i < 589824){
    int t = i - 393216;
    int j  = t & 7;
    int s  = (t >> 3) & 3;
    int c  = (t >> 5) & 255;
    int ks = (t >> 13) & 7;
    int l  = t >> 16;
    int kc = s ^ ((c >> 1) & 3);
    int k  = ks*32 + kc*8 + j;
    w2img[t] = f2bf(gw2[(l*256 + k)*256 + c]);
  } else if (i < 622592){
    int t = i - 589824;
    int o = t >> 8, k = t & 255;
    pw1bf[t] = f2bf(pw1[k*128 + o]);
  } else if (i < 626432){
    int t = i - 622592;
    int l = t / 1280;
    int r = t - l*1280;
    int bt = r >> 8, c = r & 255;
    float s = gb1[l*HD + c];
    for (int d = 0; d < BD; ++d)
      s += bond_table[bt*BD + d] * gw1[(l*576 + 512 + d)*256 + c];
    preb[(l*5 + bt)*256 + c] = s;
  } else if (i < 626447){
    int t = i - 626432;
    int l = t / 5, b = t - 5*l;
    float s = att_b[l];
    for (int d = 0; d < BD; ++d) s += bond_table[b*BD + d] * att_w[l*BD + d];
    gate_tab[t] = 1.0f / (1.0f + __expf(-s));
  } else if (i < 626703){
    pooled[i - 626447] = 0.0f;
  } else if (i < 646703){
    cnt[i - 626703] = 0;
  }
}

__global__ void init_embed_k(const float* __restrict__ x,
                             const float* __restrict__ atom_table,
                             const float* __restrict__ charge_table,
                             const float* __restrict__ hybrid_table,
                             float* __restrict__ h0,
                             float* __restrict__ out_at){
  int n = blockIdx.x, c = threadIdx.x;
  int at = (int)x[n*3 + 0]; at = at < 0 ? 0 : (at > 10 ? 10 : at);
  int hy = (int)x[n*3 + 1]; hy = hy < 0 ? 0 : (hy > 7 ? 7 : hy);
  int fc = (int)x[n*3 + 2] + 3; fc = fc < 0 ? 0 : (fc > 6 ? 6 : fc);
  float v = 0.0f;
  if (c < 64)       v = atom_table[at*64 + c];
  else if (c < 96)  v = charge_table[fc*32 + (c - 64)];
  else if (c < 128) v = hybrid_table[hy*32 + (c - 96)];
  h0[(size_t)n*HD + c] = v;
  if (c == 0) out_at[n] = (float)at;
}

// ---- counting sort by row ----
__global__ void hist_k(const int* __restrict__ eidx, int* __restrict__ cnt){
  int e = blockIdx.x*256 + threadIdx.x;
  int r = eidx[e]; r = r < 0 ? 0 : (r >= NN ? NN-1 : r);
  atomicAdd(&cnt[r], 1);
}

__launch_bounds__(1024)
__global__ void scan_k(int* __restrict__ cnt){
  __shared__ int part[1024];
  int t = threadIdx.x;
  int base = t*20;
  int loc[20];
  int s = 0;
  #pragma unroll
  for (int j = 0; j < 20; ++j){
    int idx = base + j;
    int v = (idx < NN) ? cnt[idx] : 0;
    loc[j] = v; s += v;
  }
  part[t] = s; __syncthreads();
  for (int off = 1; off < 1024; off <<= 1){
    int v = (t >= off) ? part[t-off] : 0;
    __syncthreads();
    part[t] += v;
    __syncthreads();
  }
  int run = part[t] - s;
  #pragma unroll
  for (int j = 0; j < 20; ++j){
    int idx = base + j;
    if (idx < NN){ cnt[idx] = run; run += loc[j]; }
  }
}

__global__ void scatter_k(const int* __restrict__ eidx,
                          const float* __restrict__ eattr,
                          int* __restrict__ cur,
                          int2* __restrict__ smeta){
  int e = blockIdx.x*256 + threadIdx.x;
  int r = eidx[e];        r = r < 0 ? 0 : (r >= NN ? NN-1 : r);
  int c = eidx[NE + e];   c = c < 0 ? 0 : (c >= NN ? NN-1 : c);
  int bt = (int)eattr[e]; bt = bt < 0 ? 0 : (bt > 4 ? 4 : bt);
  int pos = atomicAdd(&cur[r], 1);
  if (pos >= 0 && pos < NE){
    int2 m; m.x = r | (bt << 20); m.y = c;
    smeta[pos] = m;
  }
}

// ---- pre = bf16( h @ [W1a|W1b] ) : [NN][512] ----
__launch_bounds__(256, 2)
__global__ void pre_k(const float* __restrict__ h,
                      const u16* __restrict__ w1t,
                      u16* __restrict__ pre, int layer){
  __shared__ u16 a_lds[64*40];
  __shared__ u16 b_lds[256*40];
  const int tid = threadIdx.x;
  const int n0 = blockIdx.x * 64;
  const int half = blockIdx.y;
  const int w = tid >> 6, lane = tid & 63, g = lane >> 4, lr = lane & 15;
  const int rstage = tid >> 2, q = tid & 3;
  int arow = n0 + rstage; if (arow >= NN) arow = NN-1;
  const float* hrow = h + (size_t)arow*HD;
  const u16* bp = w1t + ((size_t)layer*512 + (size_t)half*256 + tid)*256;

  f32x4 acc[4][4];
  for (int mi = 0; mi < 4; ++mi)
    for (int nj = 0; nj < 4; ++nj)
      acc[mi][nj] = (f32x4){0.f,0.f,0.f,0.f};

  for (int ks = 0; ks < 8; ++ks){
    __syncthreads();
    {
      const float* src = hrow + ks*32 + q*8;
      float4 f0 = *(const float4*)src;
      float4 f1 = *(const float4*)(src + 4);
      uint4 av;
      av.x = pk2(f0.x,f0.y); av.y = pk2(f0.z,f0.w);
      av.z = pk2(f1.x,f1.y); av.w = pk2(f1.z,f1.w);
      *(uint4*)(a_lds + rstage*40 + q*8) = av;
    }
    {
      const u16* src = bp + ks*32;
      uint4 s0 = *(const uint4*)(src);
      uint4 s1 = *(const uint4*)(src + 8);
      uint4 s2 = *(const uint4*)(src + 16);
      uint4 s3 = *(const uint4*)(src + 24);
      u16* dst = b_lds + tid*40;
      *(uint4*)(dst)      = s0;
      *(uint4*)(dst + 8)  = s1;
      *(uint4*)(dst + 16) = s2;
      *(uint4*)(dst + 24) = s3;
    }
    __syncthreads();
    bf16x8 af[4], bfr[4];
    for (int mi = 0; mi < 4; ++mi)
      af[mi] = *(const bf16x8*)(a_lds + (mi*16 + lr)*40 + g*8);
    for (int nj = 0; nj < 4; ++nj)
      bfr[nj] = *(const bf16x8*)(b_lds + (w*64 + nj*16 + lr)*40 + g*8);
    for (int mi = 0; mi < 4; ++mi)
      for (int nj = 0; nj < 4; ++nj)
        acc[mi][nj] = __builtin_amdgcn_mfma_f32_16x16x32_bf16(af[mi], bfr[nj], acc[mi][nj], 0, 0, 0);
  }

  for (int mi = 0; mi < 4; ++mi)
    for (int nj = 0; nj < 4; ++nj)
      for (int p = 0; p < 4; ++p){
        int re = mi*16 + g*4 + p;
        int n = n0 + re;
        if (n < NN)
          pre[(size_t)n*512 + half*256 + w*64 + nj*16 + lr] = f2bf(acc[mi][nj][p]);
      }
}

// ---- fused edge kernel: 8 waves, wave-private staging, barrier-free k-loop ----
__launch_bounds__(512, 4)
__global__ void edge_msg_k(const int2* __restrict__ smeta,
                           const u16* __restrict__ pre,
                           const float* __restrict__ prebg,
                           const u16* __restrict__ w2img,
                           const float* __restrict__ b2g,
                           const float* __restrict__ gate_tab,
                           float* __restrict__ h,
                           int layer){
  __shared__ u16 b_lds[16384];     // 32KB: 2 bufs x 8 waves x (32 cols x 32 k); reused for msgs
  __shared__ u16 t_lds[64*264];    // 33792B
  __shared__ int   row_l[64];
  __shared__ float gate_l[64];

  const int tid = threadIdx.x;
  // bijective XCD-chunked swizzle: 5000 = 8 * 625
  const int bid = blockIdx.x;
  const int blk = (bid & 7)*625 + (bid >> 3);
  const int eBase = blk * 64;
  const int w = tid >> 6, lane = tid & 63, g = lane >> 4, lr = lane & 15;
  const int rstage = tid >> 3, q = tid & 7;

  const size_t wbase = (size_t)layer*65536;

  // prologue: stage W2 k-steps 0,1 (wave-private 32-col slices)
  #pragma unroll
  for (int b = 0; b < 2; ++b)
    #pragma unroll
    for (int j = 0; j < 2; ++j)
      gl_lds16(w2img + wbase + (size_t)(b*256 + w*32 + j*16)*32 + lane*8,
               b_lds + b*8192 + w*1024 + j*512);

  // one-load edge metadata
  int2 m0 = smeta[eBase + rstage];
  const int rI  = m0.x & 0xFFFFF;
  const int btI = (m0.x >> 20) & 7;
  const int cI  = m0.y;

  if (tid < 64){
    int2 mm = smeta[eBase + tid];
    row_l[tid]  = mm.x & 0xFFFFF;
    gate_l[tid] = gate_tab[layer*5 + ((mm.x >> 20) & 7)];
  }

  // ---- t = relu(pre1[row] + pre2[col] + preb[bt]) -> bf16 t_lds ----
  {
    const u16* p1 = pre + (size_t)rI*512;
    const u16* p2 = pre + (size_t)cI*512 + 256;
    const float* pb = prebg + (size_t)(layer*5 + btI)*256;
    #pragma unroll
    for (int it = 0; it < 4; ++it){
      int c0 = it*64 + q*8;
      bf16x8 v1 = *(const bf16x8*)(p1 + c0);
      bf16x8 v2 = *(const bf16x8*)(p2 + c0);
      float pv[8];
      *(float4*)(pv)     = *(const float4*)(pb + c0);
      *(float4*)(pv + 4) = *(const float4*)(pb + c0 + 4);
      float f[8];
      #pragma unroll
      for (int j = 0; j < 8; ++j){
        float s = bf2f((u16)v1[j]) + bf2f((u16)v2[j]) + pv[j];
        f[j] = s > 0.f ? s : 0.f;
      }
      uint4 ov;
      ov.x = pk2(f[0],f[1]); ov.y = pk2(f[2],f[3]);
      ov.z = pk2(f[4],f[5]); ov.w = pk2(f[6],f[7]);
      *(uint4*)(t_lds + rstage*264 + c0) = ov;
    }
  }

  __syncthreads();   // t_lds + row_l/gate_l visible to all waves

  f32x4 acc[4][2];
  for (int mi = 0; mi < 4; ++mi)
    for (int nj = 0; nj < 2; ++nj)
      acc[mi][nj] = (f32x4){0.f,0.f,0.f,0.f};

  const int sw = (g ^ ((lr >> 1) & 3)) << 3;

  // ---- GEMM2: barrier-free, wave-private double-buffered staging ----
  #pragma unroll
  for (int ks = 0; ks < 8; ++ks){
    if (ks >= 1 && ks < 7){
      #pragma unroll
      for (int j = 0; j < 2; ++j)
        gl_lds16(w2img + wbase + (size_t)((ks+1)*256 + w*32 + j*16)*32 + lane*8,
                 b_lds + ((ks+1)&1)*8192 + w*1024 + j*512);
      asm volatile("s_waitcnt vmcnt(2)" ::: "memory");
    } else if (ks == 0){
      asm volatile("s_waitcnt vmcnt(2)" ::: "memory");
    } else {
      asm volatile("s_waitcnt vmcnt(0)" ::: "memory");
    }
    const u16* bb = b_lds + (ks&1)*8192 + w*1024;
    bf16x8 af[4], bfr[2];
    for (int nj = 0; nj < 2; ++nj)
      bfr[nj] = *(const bf16x8*)(bb + (nj*16 + lr)*32 + sw);
    for (int mi = 0; mi < 4; ++mi)
      af[mi] = *(const bf16x8*)(t_lds + (mi*16 + lr)*264 + ks*32 + g*8);
    __builtin_amdgcn_s_setprio(1);
    for (int mi = 0; mi < 4; ++mi)
      for (int nj = 0; nj < 2; ++nj)
        acc[mi][nj] = __builtin_amdgcn_mfma_f32_16x16x32_bf16(af[mi], bfr[nj], acc[mi][nj], 0, 0, 0);
    __builtin_amdgcn_s_setprio(0);
  }

  // ---- epilogue: (+b2)*gate -> bf16 msgs, wave-private b_lds slices ----
  {
    float b2v[2];
    for (int nj = 0; nj < 2; ++nj) b2v[nj] = b2g[layer*HD + w*32 + nj*16 + lr];
    for (int mi = 0; mi < 4; ++mi)
      for (int nj = 0; nj < 2; ++nj){
        u16* mb = b_lds + nj*8192 + w*1024 + lr*64;
        for (int p = 0; p < 4; ++p){
          int re = mi*16 + g*4 + p;
          float val = (acc[mi][nj][p] + b2v[nj]) * gate_l[re];
          mb[(((re >> 3) ^ (lr & 7)) << 3) + (re & 7)] = f2bf(val);
        }
      }
  }
  __syncthreads();

  // ---- segmented reduction over sorted rows: 2 threads/col, 32 edges each ----
  {
    const int cl = tid & 255, half = tid >> 8;
    const u16* mb = b_lds + ((cl >> 4) & 1)*8192 + (cl >> 5)*1024 + (cl & 15)*64;
    float run = 0.f;
    int currow = row_l[half*32];
    for (int e8 = half*4; e8 < half*4 + 4; ++e8){
      bf16x8 mv = *(const bf16x8*)(mb + ((e8 ^ (cl & 7)) << 3));
      #pragma unroll
      for (int j = 0; j < 8; ++j){
        int r = row_l[e8*8 + j];
        if (r != currow){
          atomicAdd(h + (size_t)currow*HD + cl, run);
          run = 0.f; currow = r;
        }
        run += bf2f((u16)mv[j]);
      }
    }
    atomicAdd(h + (size_t)currow*HD + cl, run);
  }
}

// ---- column sums for pooling ----
__global__ void pool_k(const float* __restrict__ h,
                       float* __restrict__ pooled){
  int c = threadIdx.x;
  int r0 = blockIdx.x * 250;
  float s = 0.f;
  for (int r = r0; r < r0 + 250; ++r)
    s += h[(size_t)r*HD + c];
  atomicAdd(&pooled[c], s);
}

__global__ void fg_k(const float* __restrict__ pooled,
                     const float* __restrict__ fg_w,
                     const float* __restrict__ fg_b,
                     float* __restrict__ fg_vals){
  int o = threadIdx.x;
  int k = o >> 4, j = o & 15;
  float s = 0.f;
  for (int d = 0; d < HD; ++d) s += pooled[d] * fg_w[(size_t)k*HD*16 + d*16 + j];
  fg_vals[o] = s / (float)NN + fg_b[k*16 + j];
}

__global__ void bcast_fg_k(const float* __restrict__ fg_vals,
                           float* __restrict__ out_fg){
  __shared__ float fv[64];
  if (threadIdx.x < 64) fv[threadIdx.x] = fg_vals[threadIdx.x];
  __syncthreads();
  int i = blockIdx.x*256 + threadIdx.x;
  out_fg[i] = fv[i & 63];
}

// ---- chemical properties MLP via MFMA ----
__launch_bounds__(256, 2)
__global__ void props_mfma_k(const float* __restrict__ h,
                             const u16* __restrict__ pw1bf,
                             const float* __restrict__ pb1,
                             const float* __restrict__ pw2,
                             const float* __restrict__ pb2,
                             float* __restrict__ outp){
  __shared__ u16 a_lds[64*40];
  __shared__ u16 b2_lds[128*40];
  __shared__ u16 t2[64*136];
  __shared__ float w2s[128*32];
  const int tid = threadIdx.x;
  const int n0 = blockIdx.x*64;
  const int w = tid >> 6, lane = tid & 63, g = lane >> 4, lr = lane & 15;
  const int rstage = tid >> 2, q = tid & 3;
  int arow = n0 + rstage; if (arow >= NN) arow = NN-1;
  const float* hrow = h + (size_t)arow*HD;

  for (int j = 0; j < 4; ++j)
    *(float4*)(w2s + tid*16 + j*4) = *(const float4*)(pw2 + tid*16 + j*4);

  const int colb = tid >> 1, halfb = tid & 1;

  f32x4 acc[4][2];
  for (int mi = 0; mi < 4; ++mi)
    for (int nj = 0; nj < 2; ++nj)
      acc[mi][nj] = (f32x4){0.f,0.f,0.f,0.f};

  for (int ks = 0; ks < 8; ++ks){
    __syncthreads();
    {
      const float* src = hrow + ks*32 + q*8;
      float4 f0 = *(const float4*)src;
      float4 f1 = *(const float4*)(src + 4);
      uint4 av;
      av.x = pk2(f0.x,f0.y); av.y = pk2(f0.z,f0.w);
      av.z = pk2(f1.x,f1.y); av.w = pk2(f1.z,f1.w);
      *(uint4*)(a_lds + rstage*40 + q*8) = av;
    }
    {
      const u16* src = pw1bf + colb*256 + ks*32 + halfb*16;
      uint4 s0 = *(const uint4*)src;
      uint4 s1 = *(const uint4*)(src + 8);
      u16* dst = b2_lds + colb*40 + halfb*16;
      *(uint4*)dst = s0; *(uint4*)(dst + 8) = s1;
    }
    __syncthreads();
    bf16x8 af[4], bfr[2];
    for (int mi = 0; mi < 4; ++mi)
      af[mi] = *(const bf16x8*)(a_lds + (mi*16 + lr)*40 + g*8);
    for (int nj = 0; nj < 2; ++nj)
      bfr[nj] = *(const bf16x8*)(b2_lds + (w*32 + nj*16 + lr)*40 + g*8);
    for (int mi = 0; mi < 4; ++mi)
      for (int nj = 0; nj < 2; ++nj)
        acc[mi][nj] = __builtin_amdgcn_mfma_f32_16x16x32_bf16(af[mi], bfr[nj], acc[mi][nj], 0, 0, 0);
  }

  {
    float b1v[2];
    for (int nj = 0; nj < 2; ++nj) b1v[nj] = pb1[w*32 + nj*16 + lr];
    for (int mi = 0; mi < 4; ++mi)
      for (int nj = 0; nj < 2; ++nj){
        int colt = w*32 + nj*16 + lr;
        for (int p = 0; p < 4; ++p){
          float v = acc[mi][nj][p] + b1v[nj];
          v = v > 0.f ? v : 0.f;
          t2[(mi*16 + g*4 + p)*136 + colt] = f2bf(v);
        }
      }
  }
  __syncthreads();

  {
    int e = tid >> 2, o0 = (tid & 3)*8;
    int n = n0 + e;
    float ap[8];
    #pragma unroll
    for (int o = 0; o < 8; ++o) ap[o] = pb2[o0 + o];
    for (int d0 = 0; d0 < 16; ++d0){
      bf16x8 tv = *(const bf16x8*)(t2 + e*136 + d0*8);
      #pragma unroll
      for (int dd = 0; dd < 8; ++dd){
        float t = bf2f((u16)tv[dd]);
        const float* wr = w2s + (d0*8 + dd)*32 + o0;
        #pragma unroll
        for (int o = 0; o < 8; ++o) ap[o] += t * wr[o];
      }
    }
    if (n < NN){
      *(float4*)(outp + (size_t)n*32 + o0)     = *(float4*)(ap);
      *(float4*)(outp + (size_t)n*32 + o0 + 4) = *(float4*)(ap + 4);
    }
  }
}

extern "C" void kernel_launch(void* const* d_in, const int* in_sizes, int n_in,
                              void* d_out, int out_size, void* d_ws, size_t ws_size,
                              hipStream_t stream) {
  const float* x            = (const float*)d_in[0];
  const int*   eidx         = (const int*)  d_in[1];
  const float* eattr        = (const float*)d_in[2];
  const float* atom_table   = (const float*)d_in[4];
  const float* charge_table = (const float*)d_in[5];
  const float* hybrid_table = (const float*)d_in[6];
  const float* bond_table   = (const float*)d_in[7];
  const float* gw1          = (const float*)d_in[8];
  const float* gb1          = (const float*)d_in[9];
  const float* gw2          = (const float*)d_in[10];
  const float* gb2          = (const float*)d_in[11];
  const float* attw         = (const float*)d_in[12];
  const float* attb         = (const float*)d_in[13];
  const float* pw1          = (const float*)d_in[14];
  const float* pb1          = (const float*)d_in[15];
  const float* pw2          = (const float*)d_in[16];
  const float* pb2          = (const float*)d_in[17];
  const float* fgw          = (const float*)d_in[18];
  const float* fgb          = (const float*)d_in[19];

  float* out       = (float*)d_out;
  float* out_h     = out;
  float* out_props = out + (size_t)NN*HD;
  float* out_fg    = out_props + (size_t)NN*32;
  float* out_at    = out_fg + (size_t)NN*64;

  char* ws = (char*)d_ws;
  u16*   pre      = (u16*)  (ws + WS_PRE);
  u16*   w1t      = (u16*)  (ws + WS_W1T);
  u16*   w2img    = (u16*)  (ws + WS_W2I);
  u16*   pw1bf    = (u16*)  (ws + WS_PW1);
  float* prebg    = (float*)(ws + WS_PREB);
  float* gate_tab = (float*)(ws + WS_GATE);
  float* pooled   = (float*)(ws + WS_POOL);
  float* fg_vals  = (float*)(ws + WS_FGV);
  int*   cnt      = (int*)  (ws + WS_CNT);
  int2*  smeta    = (int2*) (ws + WS_META);

  setup_k<<<2527, 256, 0, stream>>>(gw1, gw2, pw1, bond_table, gb1, attw, attb,
                                    w1t, w2img, pw1bf, prebg, gate_tab, pooled, cnt);
  init_embed_k<<<NN, 256, 0, stream>>>(x, atom_table, charge_table, hybrid_table, out_h, out_at);

  hist_k<<<1250, 256, 0, stream>>>(eidx, cnt);
  scan_k<<<1, 1024, 0, stream>>>(cnt);
  scatter_k<<<1250, 256, 0, stream>>>(eidx, eattr, cnt, smeta);

  for (int l = 0; l < 3; ++l){
    pre_k<<<dim3(313, 2), 256, 0, stream>>>(out_h, w1t, pre, l);
    edge_msg_k<<<5000, 512, 0, stream>>>(smeta, pre, prebg, w2img,
                                         gb2, gate_tab, out_h, l);
  }

  pool_k<<<80, 256, 0, stream>>>(out_h, pooled);
  fg_k<<<1, 64, 0, stream>>>(pooled, fgw, fgb, fg_vals);
  bcast_fg_k<<<5000, 256, 0, stream>>>(fg_vals, out_fg);
  props_mfma_k<<<313, 256, 0, stream>>>(out_h, pw1bf, pb1, pw2, pb2, out_props);
}

// Round 6
// 418.563 us; speedup vs baseline: 3.8004x; 1.0127x over previous
//
#include <hip/hip_runtime.h>
#include <stdint.h>

typedef unsigned short u16;
typedef unsigned int   u32;
typedef __attribute__((ext_vector_type(8))) short bf16x8;
typedef __attribute__((ext_vector_type(4))) float f32x4;

#define NN 20000
#define NE 320000
#define HD 256
#define BD 64

// ws layout (bytes) — total ~24.4 MB
#define WS_PRE   0u           // bf16 [NN][512]                20,480,000
#define WS_W1T   20480000u    // bf16 [3][512][256]               786,432
#define WS_W2I   21266432u    // bf16 W2 swizzled image           393,216
#define WS_PW1   21659648u    // bf16 [128][256]                   65,536
#define WS_PREB  21725184u    // f32  [3][5][256]                  15,360
#define WS_GATE  21740544u    // f32  [15]
#define WS_POOL  21740608u    // f32  [256]
#define WS_FGV   21741632u    // f32  [64]
#define WS_CNT   21741888u    // int  [NN]                         80,000
#define WS_META  21821888u    // int2 [NE] sorted {row|bt<<20,col} 2,560,000

__device__ __forceinline__ u16 f2bf(float f){
  u32 u = __float_as_uint(f);
  u += 0x7fffu + ((u >> 16) & 1u);
  return (u16)(u >> 16);
}
__device__ __forceinline__ u32 pk2(float a, float b){
  return (u32)f2bf(a) | ((u32)f2bf(b) << 16);
}
__device__ __forceinline__ float bf2f(u16 u){
  return __uint_as_float((u32)u << 16);
}
// truncating bf16 pack: low16 = trunc(a), high16 = trunc(b) — 1 VALU op
__device__ __forceinline__ u32 pk2t(float a, float b){
  return __builtin_amdgcn_perm(__float_as_uint(a), __float_as_uint(b), 0x03020706u);
}
// two bf16 pairs -> relu(a+b+p) -> packed bf16 (truncated)
__device__ __forceinline__ u32 relu_pack(u32 a, u32 b, float p0, float p1){
  float a0 = __uint_as_float(a << 16);
  float a1 = __uint_as_float(a & 0xffff0000u);
  float b0 = __uint_as_float(b << 16);
  float b1 = __uint_as_float(b & 0xffff0000u);
  float s0 = fmaxf(a0 + b0 + p0, 0.f);
  float s1 = fmaxf(a1 + b1 + p1, 0.f);
  return pk2t(s0, s1);
}
__device__ __forceinline__ void gl_lds16(const u16* g, u16* l){
  __builtin_amdgcn_global_load_lds(
      (const __attribute__((address_space(1))) unsigned int*)g,
      (__attribute__((address_space(3))) unsigned int*)l, 16, 0, 0);
}

// ---- merged one-time setup: weights + preb + gate + zeros + node embedding ----
// ranges: [0,393216) w1t | [393216,589824) w2img | [589824,622592) pw1
//         [622592,626432) preb | [626432,626447) gate | [626447,626703) pooled
//         [626703,646703) cnt | [646703,1286703) node embedding (8 el/thread)
__global__ void setup_k(const float* __restrict__ gw1,
                        const float* __restrict__ gw2,
                        const float* __restrict__ pw1,
                        const float* __restrict__ bond_table,
                        const float* __restrict__ gb1,
                        const float* __restrict__ att_w,
                        const float* __restrict__ att_b,
                        const float* __restrict__ x,
                        const float* __restrict__ atom_table,
                        const float* __restrict__ charge_table,
                        const float* __restrict__ hybrid_table,
                        u16* __restrict__ w1t, u16* __restrict__ w2img,
                        u16* __restrict__ pw1bf, float* __restrict__ preb,
                        float* __restrict__ gate_tab, float* __restrict__ pooled,
                        int* __restrict__ cnt,
                        float* __restrict__ h0, float* __restrict__ out_at){
  int i = blockIdx.x*256 + threadIdx.x;
  if (i < 393216){
    int l = i >> 17;
    int r = i & 131071;
    int c = r >> 8;
    int k = r & 255;
    int srow = (c < 256) ? k : (256 + k);
    w1t[i] = f2bf(gw1[(l*576 + srow)*256 + (c & 255)]);
  } else if (i < 589824){
    int t = i - 393216;
    int j  = t & 7;
    int s  = (t >> 3) & 3;
    int c  = (t >> 5) & 255;
    int ks = (t >> 13) & 7;
    int l  = t >> 16;
    int kc = s ^ ((c >> 1) & 3);
    int k  = ks*32 + kc*8 + j;
    w2img[t] = f2bf(gw2[(l*256 + k)*256 + c]);
  } else if (i < 622592){
    int t = i - 589824;
    int o = t >> 8, k = t & 255;
    pw1bf[t] = f2bf(pw1[k*128 + o]);
  } else if (i < 626432){
    int t = i - 622592;
    int l = t / 1280;
    int r = t - l*1280;
    int bt = r >> 8, c = r & 255;
    float s = gb1[l*HD + c];
    for (int d = 0; d < BD; ++d)
      s += bond_table[bt*BD + d] * gw1[(l*576 + 512 + d)*256 + c];
    preb[(l*5 + bt)*256 + c] = s;
  } else if (i < 626447){
    int t = i - 626432;
    int l = t / 5, b = t - 5*l;
    float s = att_b[l];
    for (int d = 0; d < BD; ++d) s += bond_table[b*BD + d] * att_w[l*BD + d];
    gate_tab[t] = 1.0f / (1.0f + __expf(-s));
  } else if (i < 626703){
    pooled[i - 626447] = 0.0f;
  } else if (i < 646703){
    cnt[i - 626703] = 0;
  } else if (i < 1286703){
    int t = i - 646703;
    int n = t >> 5, sub = t & 31, c0 = sub*8;
    int at = (int)x[n*3 + 0]; at = at < 0 ? 0 : (at > 10 ? 10 : at);
    float4 v0 = {0.f,0.f,0.f,0.f}, v1 = {0.f,0.f,0.f,0.f};
    if (c0 < 64){
      v0 = *(const float4*)(atom_table + at*64 + c0);
      v1 = *(const float4*)(atom_table + at*64 + c0 + 4);
    } else if (c0 < 96){
      int fc = (int)x[n*3 + 2] + 3; fc = fc < 0 ? 0 : (fc > 6 ? 6 : fc);
      v0 = *(const float4*)(charge_table + fc*32 + (c0 - 64));
      v1 = *(const float4*)(charge_table + fc*32 + (c0 - 64) + 4);
    } else if (c0 < 128){
      int hy = (int)x[n*3 + 1]; hy = hy < 0 ? 0 : (hy > 7 ? 7 : hy);
      v0 = *(const float4*)(hybrid_table + hy*32 + (c0 - 96));
      v1 = *(const float4*)(hybrid_table + hy*32 + (c0 - 96) + 4);
    }
    *(float4*)(h0 + (size_t)n*HD + c0)     = v0;
    *(float4*)(h0 + (size_t)n*HD + c0 + 4) = v1;
    if (sub == 0) out_at[n] = (float)at;
  }
}

// ---- counting sort by row ----
__global__ void hist_k(const int* __restrict__ eidx, int* __restrict__ cnt){
  int e = blockIdx.x*256 + threadIdx.x;
  int r = eidx[e]; r = r < 0 ? 0 : (r >= NN ? NN-1 : r);
  atomicAdd(&cnt[r], 1);
}

__launch_bounds__(1024)
__global__ void scan_k(int* __restrict__ cnt){
  __shared__ int part[1024];
  int t = threadIdx.x;
  int base = t*20;
  int loc[20];
  int s = 0;
  #pragma unroll
  for (int j = 0; j < 20; ++j){
    int idx = base + j;
    int v = (idx < NN) ? cnt[idx] : 0;
    loc[j] = v; s += v;
  }
  part[t] = s; __syncthreads();
  for (int off = 1; off < 1024; off <<= 1){
    int v = (t >= off) ? part[t-off] : 0;
    __syncthreads();
    part[t] += v;
    __syncthreads();
  }
  int run = part[t] - s;
  #pragma unroll
  for (int j = 0; j < 20; ++j){
    int idx = base + j;
    if (idx < NN){ cnt[idx] = run; run += loc[j]; }
  }
}

__global__ void scatter_k(const int* __restrict__ eidx,
                          const float* __restrict__ eattr,
                          int* __restrict__ cur,
                          int2* __restrict__ smeta){
  int e = blockIdx.x*256 + threadIdx.x;
  int r = eidx[e];        r = r < 0 ? 0 : (r >= NN ? NN-1 : r);
  int c = eidx[NE + e];   c = c < 0 ? 0 : (c >= NN ? NN-1 : c);
  int bt = (int)eattr[e]; bt = bt < 0 ? 0 : (bt > 4 ? 4 : bt);
  int pos = atomicAdd(&cur[r], 1);
  if (pos >= 0 && pos < NE){
    int2 m; m.x = r | (bt << 20); m.y = c;
    smeta[pos] = m;
  }
}

// ---- pre = bf16( h @ [W1a|W1b] ) : [NN][512] ----
__launch_bounds__(256, 4)
__global__ void pre_k(const float* __restrict__ h,
                      const u16* __restrict__ w1t,
                      u16* __restrict__ pre, int layer){
  __shared__ u16 a_lds[64*40];
  __shared__ u16 b_lds[256*40];
  const int tid = threadIdx.x;
  const int n0 = blockIdx.x * 64;
  const int half = blockIdx.y;
  const int w = tid >> 6, lane = tid & 63, g = lane >> 4, lr = lane & 15;
  const int rstage = tid >> 2, q = tid & 3;
  int arow = n0 + rstage; if (arow >= NN) arow = NN-1;
  const float* hrow = h + (size_t)arow*HD;
  const u16* bp = w1t + ((size_t)layer*512 + (size_t)half*256 + tid)*256;

  f32x4 acc[4][4];
  for (int mi = 0; mi < 4; ++mi)
    for (int nj = 0; nj < 4; ++nj)
      acc[mi][nj] = (f32x4){0.f,0.f,0.f,0.f};

  for (int ks = 0; ks < 8; ++ks){
    __syncthreads();
    {
      const float* src = hrow + ks*32 + q*8;
      float4 f0 = *(const float4*)src;
      float4 f1 = *(const float4*)(src + 4);
      uint4 av;
      av.x = pk2(f0.x,f0.y); av.y = pk2(f0.z,f0.w);
      av.z = pk2(f1.x,f1.y); av.w = pk2(f1.z,f1.w);
      *(uint4*)(a_lds + rstage*40 + q*8) = av;
    }
    {
      const u16* src = bp + ks*32;
      uint4 s0 = *(const uint4*)(src);
      uint4 s1 = *(const uint4*)(src + 8);
      uint4 s2 = *(const uint4*)(src + 16);
      uint4 s3 = *(const uint4*)(src + 24);
      u16* dst = b_lds + tid*40;
      *(uint4*)(dst)      = s0;
      *(uint4*)(dst + 8)  = s1;
      *(uint4*)(dst + 16) = s2;
      *(uint4*)(dst + 24) = s3;
    }
    __syncthreads();
    bf16x8 af[4], bfr[4];
    for (int mi = 0; mi < 4; ++mi)
      af[mi] = *(const bf16x8*)(a_lds + (mi*16 + lr)*40 + g*8);
    for (int nj = 0; nj < 4; ++nj)
      bfr[nj] = *(const bf16x8*)(b_lds + (w*64 + nj*16 + lr)*40 + g*8);
    for (int mi = 0; mi < 4; ++mi)
      for (int nj = 0; nj < 4; ++nj)
        acc[mi][nj] = __builtin_amdgcn_mfma_f32_16x16x32_bf16(af[mi], bfr[nj], acc[mi][nj], 0, 0, 0);
  }

  for (int mi = 0; mi < 4; ++mi)
    for (int nj = 0; nj < 4; ++nj)
      for (int p = 0; p < 4; ++p){
        int re = mi*16 + g*4 + p;
        int n = n0 + re;
        if (n < NN)
          pre[(size_t)n*512 + half*256 + w*64 + nj*16 + lr] = f2bf(acc[mi][nj][p]);
      }
}

// ---- fused edge kernel: 8 waves, wave-private staging, barrier-free k-loop ----
__launch_bounds__(512, 4)
__global__ void edge_msg_k(const int2* __restrict__ smeta,
                           const u16* __restrict__ pre,
                           const float* __restrict__ prebg,
                           const u16* __restrict__ w2img,
                           const float* __restrict__ b2g,
                           const float* __restrict__ gate_tab,
                           float* __restrict__ h,
                           int layer){
  __shared__ u16 b_lds[16384];     // 32KB: 2 bufs x 8 waves x (32 cols x 32 k); reused for msgs
  __shared__ u16 t_lds[64*264];    // 33792B
  __shared__ int   row_l[64];
  __shared__ float gate_l[64];

  const int tid = threadIdx.x;
  // bijective XCD-chunked swizzle: 5000 = 8 * 625
  const int bid = blockIdx.x;
  const int blk = (bid & 7)*625 + (bid >> 3);
  const int eBase = blk * 64;
  const int w = tid >> 6, lane = tid & 63, g = lane >> 4, lr = lane & 15;
  const int rstage = tid >> 3, q = tid & 7;

  const size_t wbase = (size_t)layer*65536;

  // prologue: stage W2 k-steps 0,1 (wave-private 32-col slices)
  #pragma unroll
  for (int b = 0; b < 2; ++b)
    #pragma unroll
    for (int j = 0; j < 2; ++j)
      gl_lds16(w2img + wbase + (size_t)(b*256 + w*32 + j*16)*32 + lane*8,
               b_lds + b*8192 + w*1024 + j*512);

  // one-load edge metadata
  int2 m0 = smeta[eBase + rstage];
  const int rI  = m0.x & 0xFFFFF;
  const int btI = (m0.x >> 20) & 7;
  const int cI  = m0.y;

  if (tid < 64){
    int2 mm = smeta[eBase + tid];
    row_l[tid]  = mm.x & 0xFFFFF;
    gate_l[tid] = gate_tab[layer*5 + ((mm.x >> 20) & 7)];
  }

  // ---- t = relu(pre1[row] + pre2[col] + preb[bt]) -> bf16 t_lds (perm-packed) ----
  {
    const u16* p1 = pre + (size_t)rI*512;
    const u16* p2 = pre + (size_t)cI*512 + 256;
    const float* pb = prebg + (size_t)(layer*5 + btI)*256;
    #pragma unroll
    for (int it = 0; it < 4; ++it){
      int c0 = it*64 + q*8;
      uint4 v1 = *(const uint4*)(p1 + c0);
      uint4 v2 = *(const uint4*)(p2 + c0);
      float4 pa = *(const float4*)(pb + c0);
      float4 pc = *(const float4*)(pb + c0 + 4);
      uint4 ov;
      ov.x = relu_pack(v1.x, v2.x, pa.x, pa.y);
      ov.y = relu_pack(v1.y, v2.y, pa.z, pa.w);
      ov.z = relu_pack(v1.z, v2.z, pc.x, pc.y);
      ov.w = relu_pack(v1.w, v2.w, pc.z, pc.w);
      *(uint4*)(t_lds + rstage*264 + c0) = ov;
    }
  }

  __syncthreads();   // t_lds + row_l/gate_l visible to all waves

  f32x4 acc[4][2];
  for (int mi = 0; mi < 4; ++mi)
    for (int nj = 0; nj < 2; ++nj)
      acc[mi][nj] = (f32x4){0.f,0.f,0.f,0.f};

  const int sw = (g ^ ((lr >> 1) & 3)) << 3;

  // ---- GEMM2: barrier-free, wave-private double-buffered staging ----
  #pragma unroll
  for (int ks = 0; ks < 8; ++ks){
    if (ks >= 1 && ks < 7){
      #pragma unroll
      for (int j = 0; j < 2; ++j)
        gl_lds16(w2img + wbase + (size_t)((ks+1)*256 + w*32 + j*16)*32 + lane*8,
                 b_lds + ((ks+1)&1)*8192 + w*1024 + j*512);
      asm volatile("s_waitcnt vmcnt(2)" ::: "memory");
    } else if (ks == 0){
      asm volatile("s_waitcnt vmcnt(2)" ::: "memory");
    } else {
      asm volatile("s_waitcnt vmcnt(0)" ::: "memory");
    }
    const u16* bb = b_lds + (ks&1)*8192 + w*1024;
    bf16x8 af[4], bfr[2];
    for (int nj = 0; nj < 2; ++nj)
      bfr[nj] = *(const bf16x8*)(bb + (nj*16 + lr)*32 + sw);
    for (int mi = 0; mi < 4; ++mi)
      af[mi] = *(const bf16x8*)(t_lds + (mi*16 + lr)*264 + ks*32 + g*8);
    __builtin_amdgcn_s_setprio(1);
    for (int mi = 0; mi < 4; ++mi)
      for (int nj = 0; nj < 2; ++nj)
        acc[mi][nj] = __builtin_amdgcn_mfma_f32_16x16x32_bf16(af[mi], bfr[nj], acc[mi][nj], 0, 0, 0);
    __builtin_amdgcn_s_setprio(0);
  }

  // ---- epilogue: (+b2)*gate -> bf16 msgs, wave-private b_lds, b64 stores ----
  {
    float b2v[2];
    for (int nj = 0; nj < 2; ++nj) b2v[nj] = b2g[layer*HD + w*32 + nj*16 + lr];
    for (int mi = 0; mi < 4; ++mi)
      for (int nj = 0; nj < 2; ++nj){
        u16* mb = b_lds + nj*8192 + w*1024 + lr*64;
        float v[4];
        #pragma unroll
        for (int p = 0; p < 4; ++p){
          int re = mi*16 + g*4 + p;
          v[p] = (acc[mi][nj][p] + b2v[nj]) * gate_l[re];
        }
        int slot = (mi*2 + (g >> 1)) ^ (lr & 7);
        uint2 pkv; pkv.x = pk2t(v[0], v[1]); pkv.y = pk2t(v[2], v[3]);
        *(uint2*)(mb + slot*8 + (g & 1)*4) = pkv;
      }
  }
  __syncthreads();

  // ---- segmented reduction over sorted rows: 2 threads/col, 32 edges each ----
  {
    const int cl = tid & 255, half = tid >> 8;
    const u16* mb = b_lds + ((cl >> 4) & 1)*8192 + (cl >> 5)*1024 + (cl & 15)*64;
    float run = 0.f;
    int currow = row_l[half*32];
    for (int e8 = half*4; e8 < half*4 + 4; ++e8){
      bf16x8 mv = *(const bf16x8*)(mb + ((e8 ^ (cl & 7)) << 3));
      #pragma unroll
      for (int j = 0; j < 8; ++j){
        int r = row_l[e8*8 + j];
        if (r != currow){
          atomicAdd(h + (size_t)currow*HD + cl, run);
          run = 0.f; currow = r;
        }
        run += bf2f((u16)mv[j]);
      }
    }
    atomicAdd(h + (size_t)currow*HD + cl, run);
  }
}

// ---- column sums for pooling ----
__global__ void pool_k(const float* __restrict__ h,
                       float* __restrict__ pooled){
  int c = threadIdx.x;
  int r0 = blockIdx.x * 50;
  float s = 0.f;
  for (int r = r0; r < r0 + 50; ++r)
    s += h[(size_t)r*HD + c];
  atomicAdd(&pooled[c], s);
}

// ---- fg from pooled (recomputed per block, tiny) + broadcast ----
__global__ void bcast_fg_k(const float* __restrict__ pooled,
                           const float* __restrict__ fg_w,
                           const float* __restrict__ fg_b,
                           float* __restrict__ out_fg){
  __shared__ float fv[64];
  int tid = threadIdx.x;
  if (tid < 64){
    int k = tid >> 4, j = tid & 15;
    float s = 0.f;
    for (int d = 0; d < HD; ++d) s += pooled[d] * fg_w[(size_t)k*HD*16 + d*16 + j];
    fv[tid] = s / (float)NN + fg_b[k*16 + j];
  }
  __syncthreads();
  int i = blockIdx.x*256 + tid;
  out_fg[i] = fv[i & 63];
}

// ---- chemical properties MLP via MFMA ----
__launch_bounds__(256, 3)
__global__ void props_mfma_k(const float* __restrict__ h,
                             const u16* __restrict__ pw1bf,
                             const float* __restrict__ pb1,
                             const float* __restrict__ pw2,
                             const float* __restrict__ pb2,
                             float* __restrict__ outp){
  __shared__ u16 a_lds[64*40];
  __shared__ u16 b2_lds[128*40];
  __shared__ u16 t2[64*136];
  __shared__ float w2s[128*32];
  const int tid = threadIdx.x;
  const int n0 = blockIdx.x*64;
  const int w = tid >> 6, lane = tid & 63, g = lane >> 4, lr = lane & 15;
  const int rstage = tid >> 2, q = tid & 3;
  int arow = n0 + rstage; if (arow >= NN) arow = NN-1;
  const float* hrow = h + (size_t)arow*HD;

  for (int j = 0; j < 4; ++j)
    *(float4*)(w2s + tid*16 + j*4) = *(const float4*)(pw2 + tid*16 + j*4);

  const int colb = tid >> 1, halfb = tid & 1;

  f32x4 acc[4][2];
  for (int mi = 0; mi < 4; ++mi)
    for (int nj = 0; nj < 2; ++nj)
      acc[mi][nj] = (f32x4){0.f,0.f,0.f,0.f};

  for (int ks = 0; ks < 8; ++ks){
    __syncthreads();
    {
      const float* src = hrow + ks*32 + q*8;
      float4 f0 = *(const float4*)src;
      float4 f1 = *(const float4*)(src + 4);
      uint4 av;
      av.x = pk2(f0.x,f0.y); av.y = pk2(f0.z,f0.w);
      av.z = pk2(f1.x,f1.y); av.w = pk2(f1.z,f1.w);
      *(uint4*)(a_lds + rstage*40 + q*8) = av;
    }
    {
      const u16* src = pw1bf + colb*256 + ks*32 + halfb*16;
      uint4 s0 = *(const uint4*)src;
      uint4 s1 = *(const uint4*)(src + 8);
      u16* dst = b2_lds + colb*40 + halfb*16;
      *(uint4*)dst = s0; *(uint4*)(dst + 8) = s1;
    }
    __syncthreads();
    bf16x8 af[4], bfr[2];
    for (int mi = 0; mi < 4; ++mi)
      af[mi] = *(const bf16x8*)(a_lds + (mi*16 + lr)*40 + g*8);
    for (int nj = 0; nj < 2; ++nj)
      bfr[nj] = *(const bf16x8*)(b2_lds + (w*32 + nj*16 + lr)*40 + g*8);
    for (int mi = 0; mi < 4; ++mi)
      for (int nj = 0; nj < 2; ++nj)
        acc[mi][nj] = __builtin_amdgcn_mfma_f32_16x16x32_bf16(af[mi], bfr[nj], acc[mi][nj], 0, 0, 0);
  }

  {
    float b1v[2];
    for (int nj = 0; nj < 2; ++nj) b1v[nj] = pb1[w*32 + nj*16 + lr];
    for (int mi = 0; mi < 4; ++mi)
      for (int nj = 0; nj < 2; ++nj){
        int colt = w*32 + nj*16 + lr;
        for (int p = 0; p < 4; ++p){
          float v = acc[mi][nj][p] + b1v[nj];
          v = v > 0.f ? v : 0.f;
          t2[(mi*16 + g*4 + p)*136 + colt] = f2bf(v);
        }
      }
  }
  __syncthreads();

  {
    int e = tid >> 2, o0 = (tid & 3)*8;
    int n = n0 + e;
    float ap[8];
    #pragma unroll
    for (int o = 0; o < 8; ++o) ap[o] = pb2[o0 + o];
    for (int d0 = 0; d0 < 16; ++d0){
      bf16x8 tv = *(const bf16x8*)(t2 + e*136 + d0*8);
      #pragma unroll
      for (int dd = 0; dd < 8; ++dd){
        float t = bf2f((u16)tv[dd]);
        const float* wr = w2s + (d0*8 + dd)*32 + o0;
        #pragma unroll
        for (int o = 0; o < 8; ++o) ap[o] += t * wr[o];
      }
    }
    if (n < NN){
      *(float4*)(outp + (size_t)n*32 + o0)     = *(float4*)(ap);
      *(float4*)(outp + (size_t)n*32 + o0 + 4) = *(float4*)(ap + 4);
    }
  }
}

extern "C" void kernel_launch(void* const* d_in, const int* in_sizes, int n_in,
                              void* d_out, int out_size, void* d_ws, size_t ws_size,
                              hipStream_t stream) {
  const float* x            = (const float*)d_in[0];
  const int*   eidx         = (const int*)  d_in[1];
  const float* eattr        = (const float*)d_in[2];
  const float* atom_table   = (const float*)d_in[4];
  const float* charge_table = (const float*)d_in[5];
  const float* hybrid_table = (const float*)d_in[6];
  const float* bond_table   = (const float*)d_in[7];
  const float* gw1          = (const float*)d_in[8];
  const float* gb1          = (const float*)d_in[9];
  const float* gw2          = (const float*)d_in[10];
  const float* gb2          = (const float*)d_in[11];
  const float* attw         = (const float*)d_in[12];
  const float* attb         = (const float*)d_in[13];
  const float* pw1          = (const float*)d_in[14];
  const float* pb1          = (const float*)d_in[15];
  const float* pw2          = (const float*)d_in[16];
  const float* pb2          = (const float*)d_in[17];
  const float* fgw          = (const float*)d_in[18];
  const float* fgb          = (const float*)d_in[19];

  float* out       = (float*)d_out;
  float* out_h     = out;
  float* out_props = out + (size_t)NN*HD;
  float* out_fg    = out_props + (size_t)NN*32;
  float* out_at    = out_fg + (size_t)NN*64;

  char* ws = (char*)d_ws;
  u16*   pre      = (u16*)  (ws + WS_PRE);
  u16*   w1t      = (u16*)  (ws + WS_W1T);
  u16*   w2img    = (u16*)  (ws + WS_W2I);
  u16*   pw1bf    = (u16*)  (ws + WS_PW1);
  float* prebg    = (float*)(ws + WS_PREB);
  float* gate_tab = (float*)(ws + WS_GATE);
  float* pooled   = (float*)(ws + WS_POOL);
  int*   cnt      = (int*)  (ws + WS_CNT);
  int2*  smeta    = (int2*) (ws + WS_META);

  setup_k<<<5027, 256, 0, stream>>>(gw1, gw2, pw1, bond_table, gb1, attw, attb,
                                    x, atom_table, charge_table, hybrid_table,
                                    w1t, w2img, pw1bf, prebg, gate_tab, pooled,
                                    cnt, out_h, out_at);

  hist_k<<<1250, 256, 0, stream>>>(eidx, cnt);
  scan_k<<<1, 1024, 0, stream>>>(cnt);
  scatter_k<<<1250, 256, 0, stream>>>(eidx, eattr, cnt, smeta);

  for (int l = 0; l < 3; ++l){
    pre_k<<<dim3(313, 2), 256, 0, stream>>>(out_h, w1t, pre, l);
    edge_msg_k<<<5000, 512, 0, stream>>>(smeta, pre, prebg, w2img,
                                         gb2, gate_tab, out_h, l);
  }

  pool_k<<<400, 256, 0, stream>>>(out_h, pooled);
  props_mfma_k<<<313, 256, 0, stream>>>(out_h, pw1bf, pb1, pw2, pb2, out_props);
  bcast_fg_k<<<5000, 256, 0, stream>>>(pooled, fgw, fgb, out_fg);
}

// Round 7
// 382.904 us; speedup vs baseline: 4.1544x; 1.0931x over previous
//
#include <hip/hip_runtime.h>
#include <stdint.h>

typedef unsigned short u16;
typedef unsigned int   u32;
typedef unsigned long long u64;
typedef __attribute__((ext_vector_type(8))) short bf16x8;
typedef __attribute__((ext_vector_type(4))) float f32x4;

#define NN 20000
#define NE 320000
#define HD 256
#define BD 64

// ws layout (bytes) — total ~24.4 MB
#define WS_PRE   0u           // bf16 [NN][512]                20,480,000
#define WS_W1T   20480000u    // bf16 [3][512][256]               786,432
#define WS_W2I   21266432u    // bf16 W2 swizzled image           393,216
#define WS_PW1   21659648u    // bf16 [128][256]                   65,536
#define WS_PREB  21725184u    // f32  [3][5][256]                  15,360
#define WS_GATE  21740544u    // f32  [15]
#define WS_POOL  21740608u    // f32  [256]
#define WS_FGV   21741632u    // f32  [64]
#define WS_CNT   21741888u    // int  [NN]                         80,000
#define WS_META  21821888u    // int2 [NE] sorted {row|bt<<20,col} 2,560,000

__device__ __forceinline__ u16 f2bf(float f){
  u32 u = __float_as_uint(f);
  u += 0x7fffu + ((u >> 16) & 1u);
  return (u16)(u >> 16);
}
__device__ __forceinline__ u32 pk2(float a, float b){
  return (u32)f2bf(a) | ((u32)f2bf(b) << 16);
}
__device__ __forceinline__ float bf2f(u16 u){
  return __uint_as_float((u32)u << 16);
}
// truncating bf16 pack: low16 = trunc(a), high16 = trunc(b) — 1 VALU op
__device__ __forceinline__ u32 pk2t(float a, float b){
  return __builtin_amdgcn_perm(__float_as_uint(a), __float_as_uint(b), 0x03020706u);
}
// two bf16 pairs -> relu(a+b+p) -> packed bf16 (truncated)
__device__ __forceinline__ u32 relu_pack(u32 a, u32 b, float p0, float p1){
  float a0 = __uint_as_float(a << 16);
  float a1 = __uint_as_float(a & 0xffff0000u);
  float b0 = __uint_as_float(b << 16);
  float b1 = __uint_as_float(b & 0xffff0000u);
  float s0 = fmaxf(a0 + b0 + p0, 0.f);
  float s1 = fmaxf(a1 + b1 + p1, 0.f);
  return pk2t(s0, s1);
}
__device__ __forceinline__ void gl_lds16(const u16* g, u16* l){
  __builtin_amdgcn_global_load_lds(
      (const __attribute__((address_space(1))) unsigned int*)g,
      (__attribute__((address_space(3))) unsigned int*)l, 16, 0, 0);
}

// ---- merged one-time setup (read-coalesced transposes) ----
// ranges: [0,442368) gw1->w1t | [442368,638976) gw2->w2img | [638976,671744) pw1
//         [671744,675584) preb | [675584,675599) gate | [675599,675855) pooled
//         [675855,695855) cnt | [695855,1335855) node embedding
__global__ void setup_k(const float* __restrict__ gw1,
                        const float* __restrict__ gw2,
                        const float* __restrict__ pw1,
                        const float* __restrict__ bond_table,
                        const float* __restrict__ gb1,
                        const float* __restrict__ att_w,
                        const float* __restrict__ att_b,
                        const float* __restrict__ x,
                        const float* __restrict__ atom_table,
                        const float* __restrict__ charge_table,
                        const float* __restrict__ hybrid_table,
                        u16* __restrict__ w1t, u16* __restrict__ w2img,
                        u16* __restrict__ pw1bf, float* __restrict__ preb,
                        float* __restrict__ gate_tab, float* __restrict__ pooled,
                        int* __restrict__ cnt,
                        float* __restrict__ h0, float* __restrict__ out_at){
  int i = blockIdx.x*256 + threadIdx.x;
  if (i < 442368){
    // coalesced read of gw1, scattered write to w1t[l][dc][k]
    float v = gw1[i];
    int l = i / 147456;
    int r = i - l*147456;
    int srow = r >> 8, c = r & 255;
    if (srow < 512){
      int dc = (srow < 256) ? c : (256 + c);
      w1t[((size_t)l*512 + dc)*256 + (srow & 255)] = f2bf(v);
    }
  } else if (i < 638976){
    int t = i - 442368;
    float v = gw2[t];
    int l = t >> 16;
    int rest = t & 65535;
    int k = rest >> 8, c = rest & 255;
    int ks = k >> 5, k5 = k & 31;
    int kc = k5 >> 3, j = k5 & 7;
    int s = kc ^ ((c >> 1) & 3);
    w2img[(((l*8 + ks)*256 + c)*4 + s)*8 + j] = f2bf(v);
  } else if (i < 671744){
    int t = i - 638976;
    float v = pw1[t];
    int k = t >> 7, o = t & 127;
    pw1bf[o*256 + k] = f2bf(v);
  } else if (i < 675584){
    int t = i - 671744;
    int l = t / 1280;
    int r = t - l*1280;
    int bt = r >> 8, c = r & 255;
    float s = gb1[l*HD + c];
    for (int d = 0; d < BD; ++d)
      s += bond_table[bt*BD + d] * gw1[(l*576 + 512 + d)*256 + c];
    preb[(l*5 + bt)*256 + c] = s;
  } else if (i < 675599){
    int t = i - 675584;
    int l = t / 5, b = t - 5*l;
    float s = att_b[l];
    for (int d = 0; d < BD; ++d) s += bond_table[b*BD + d] * att_w[l*BD + d];
    gate_tab[t] = 1.0f / (1.0f + __expf(-s));
  } else if (i < 675855){
    pooled[i - 675599] = 0.0f;
  } else if (i < 695855){
    cnt[i - 675855] = 0;
  } else if (i < 1335855){
    int t = i - 695855;
    int n = t >> 5, sub = t & 31, c0 = sub*8;
    int at = (int)x[n*3 + 0]; at = at < 0 ? 0 : (at > 10 ? 10 : at);
    float4 v0 = {0.f,0.f,0.f,0.f}, v1 = {0.f,0.f,0.f,0.f};
    if (c0 < 64){
      v0 = *(const float4*)(atom_table + at*64 + c0);
      v1 = *(const float4*)(atom_table + at*64 + c0 + 4);
    } else if (c0 < 96){
      int fc = (int)x[n*3 + 2] + 3; fc = fc < 0 ? 0 : (fc > 6 ? 6 : fc);
      v0 = *(const float4*)(charge_table + fc*32 + (c0 - 64));
      v1 = *(const float4*)(charge_table + fc*32 + (c0 - 64) + 4);
    } else if (c0 < 128){
      int hy = (int)x[n*3 + 1]; hy = hy < 0 ? 0 : (hy > 7 ? 7 : hy);
      v0 = *(const float4*)(hybrid_table + hy*32 + (c0 - 96));
      v1 = *(const float4*)(hybrid_table + hy*32 + (c0 - 96) + 4);
    }
    *(float4*)(h0 + (size_t)n*HD + c0)     = v0;
    *(float4*)(h0 + (size_t)n*HD + c0 + 4) = v1;
    if (sub == 0) out_at[n] = (float)at;
  }
}

// ---- counting sort by row ----
__global__ void hist_k(const int* __restrict__ eidx, int* __restrict__ cnt){
  int e = blockIdx.x*256 + threadIdx.x;
  int r = eidx[e]; r = r < 0 ? 0 : (r >= NN ? NN-1 : r);
  atomicAdd(&cnt[r], 1);
}

__launch_bounds__(1024)
__global__ void scan_k(int* __restrict__ cnt){
  __shared__ int part[1024];
  int t = threadIdx.x;
  int base = t*20;
  int loc[20];
  int s = 0;
  #pragma unroll
  for (int j = 0; j < 20; ++j){
    int idx = base + j;
    int v = (idx < NN) ? cnt[idx] : 0;
    loc[j] = v; s += v;
  }
  part[t] = s; __syncthreads();
  for (int off = 1; off < 1024; off <<= 1){
    int v = (t >= off) ? part[t-off] : 0;
    __syncthreads();
    part[t] += v;
    __syncthreads();
  }
  int run = part[t] - s;
  #pragma unroll
  for (int j = 0; j < 20; ++j){
    int idx = base + j;
    if (idx < NN){ cnt[idx] = run; run += loc[j]; }
  }
}

__global__ void scatter_k(const int* __restrict__ eidx,
                          const float* __restrict__ eattr,
                          int* __restrict__ cur,
                          int2* __restrict__ smeta){
  int e = blockIdx.x*256 + threadIdx.x;
  int r = eidx[e];        r = r < 0 ? 0 : (r >= NN ? NN-1 : r);
  int c = eidx[NE + e];   c = c < 0 ? 0 : (c >= NN ? NN-1 : c);
  int bt = (int)eattr[e]; bt = bt < 0 ? 0 : (bt > 4 ? 4 : bt);
  int pos = atomicAdd(&cur[r], 1);
  if (pos >= 0 && pos < NE){
    int2 m; m.x = r | (bt << 20); m.y = c;
    smeta[pos] = m;
  }
}

// ---- pre = bf16( h @ [W1a|W1b] ) : [NN][512] ----
__launch_bounds__(256, 4)
__global__ void pre_k(const float* __restrict__ h,
                      const u16* __restrict__ w1t,
                      u16* __restrict__ pre, int layer){
  __shared__ u16 a_lds[64*40];
  __shared__ u16 b_lds[256*40];
  const int tid = threadIdx.x;
  const int n0 = blockIdx.x * 64;
  const int half = blockIdx.y;
  const int w = tid >> 6, lane = tid & 63, g = lane >> 4, lr = lane & 15;
  const int rstage = tid >> 2, q = tid & 3;
  int arow = n0 + rstage; if (arow >= NN) arow = NN-1;
  const float* hrow = h + (size_t)arow*HD;
  const u16* bp = w1t + ((size_t)layer*512 + (size_t)half*256 + tid)*256;

  f32x4 acc[4][4];
  for (int mi = 0; mi < 4; ++mi)
    for (int nj = 0; nj < 4; ++nj)
      acc[mi][nj] = (f32x4){0.f,0.f,0.f,0.f};

  for (int ks = 0; ks < 8; ++ks){
    __syncthreads();
    {
      const float* src = hrow + ks*32 + q*8;
      float4 f0 = *(const float4*)src;
      float4 f1 = *(const float4*)(src + 4);
      uint4 av;
      av.x = pk2(f0.x,f0.y); av.y = pk2(f0.z,f0.w);
      av.z = pk2(f1.x,f1.y); av.w = pk2(f1.z,f1.w);
      *(uint4*)(a_lds + rstage*40 + q*8) = av;
    }
    {
      const u16* src = bp + ks*32;
      uint4 s0 = *(const uint4*)(src);
      uint4 s1 = *(const uint4*)(src + 8);
      uint4 s2 = *(const uint4*)(src + 16);
      uint4 s3 = *(const uint4*)(src + 24);
      u16* dst = b_lds + tid*40;
      *(uint4*)(dst)      = s0;
      *(uint4*)(dst + 8)  = s1;
      *(uint4*)(dst + 16) = s2;
      *(uint4*)(dst + 24) = s3;
    }
    __syncthreads();
    bf16x8 af[4], bfr[4];
    for (int mi = 0; mi < 4; ++mi)
      af[mi] = *(const bf16x8*)(a_lds + (mi*16 + lr)*40 + g*8);
    for (int nj = 0; nj < 4; ++nj)
      bfr[nj] = *(const bf16x8*)(b_lds + (w*64 + nj*16 + lr)*40 + g*8);
    for (int mi = 0; mi < 4; ++mi)
      for (int nj = 0; nj < 4; ++nj)
        acc[mi][nj] = __builtin_amdgcn_mfma_f32_16x16x32_bf16(af[mi], bfr[nj], acc[mi][nj], 0, 0, 0);
  }

  for (int mi = 0; mi < 4; ++mi)
    for (int nj = 0; nj < 4; ++nj)
      for (int p = 0; p < 4; ++p){
        int re = mi*16 + g*4 + p;
        int n = n0 + re;
        if (n < NN)
          pre[(size_t)n*512 + half*256 + w*64 + nj*16 + lr] = f2bf(acc[mi][nj][p]);
      }
}

// ---- fused edge kernel: 8 waves, wave-private staging, barrier-free k-loop,
//      ballot-mask uniform segmented reduce ----
__launch_bounds__(512, 4)
__global__ void edge_msg_k(const int2* __restrict__ smeta,
                           const u16* __restrict__ pre,
                           const float* __restrict__ prebg,
                           const u16* __restrict__ w2img,
                           const float* __restrict__ b2g,
                           const float* __restrict__ gate_tab,
                           float* __restrict__ h,
                           int layer){
  __shared__ u16 b_lds[16384];     // 32KB: 2 bufs x 8 waves x (32 cols x 32 k); reused for msgs
  __shared__ u16 t_lds[64*264];    // 33792B
  __shared__ int   row_l[64];
  __shared__ float gate_l[64];
  __shared__ u64   mask_l;

  const int tid = threadIdx.x;
  // bijective XCD-chunked swizzle: 5000 = 8 * 625
  const int bid = blockIdx.x;
  const int blk = (bid & 7)*625 + (bid >> 3);
  const int eBase = blk * 64;
  const int w = tid >> 6, lane = tid & 63, g = lane >> 4, lr = lane & 15;
  const int rstage = tid >> 3, q = tid & 7;

  const size_t wbase = (size_t)layer*65536;

  // prologue: stage W2 k-steps 0,1 (wave-private 32-col slices)
  #pragma unroll
  for (int b = 0; b < 2; ++b)
    #pragma unroll
    for (int j = 0; j < 2; ++j)
      gl_lds16(w2img + wbase + (size_t)(b*256 + w*32 + j*16)*32 + lane*8,
               b_lds + b*8192 + w*1024 + j*512);

  // one-load edge metadata
  int2 m0 = smeta[eBase + rstage];
  const int rI  = m0.x & 0xFFFFF;
  const int btI = (m0.x >> 20) & 7;
  const int cI  = m0.y;

  if (tid < 64){
    int2 mm = smeta[eBase + tid];
    int r = mm.x & 0xFFFFF;
    row_l[tid]  = r;
    gate_l[tid] = gate_tab[layer*5 + ((mm.x >> 20) & 7)];
    int rprev = __shfl_up(r, 1);
    bool fl = (tid > 0) && (r != rprev);
    u64 mk = __ballot(fl);
    if (tid == 0) mask_l = mk;
  }

  // ---- t = relu(pre1[row] + pre2[col] + preb[bt]) -> bf16 t_lds ----
  {
    const u16* p1 = pre + (size_t)rI*512;
    const u16* p2 = pre + (size_t)cI*512 + 256;
    const float* pb = prebg + (size_t)(layer*5 + btI)*256;
    uint4 v1[4], v2[4];
    #pragma unroll
    for (int it = 0; it < 4; ++it){
      int c0 = it*64 + q*8;
      v1[it] = *(const uint4*)(p1 + c0);
      v2[it] = *(const uint4*)(p2 + c0);
    }
    #pragma unroll
    for (int it = 0; it < 4; ++it){
      int c0 = it*64 + q*8;
      float4 pa = *(const float4*)(pb + c0);
      float4 pc = *(const float4*)(pb + c0 + 4);
      uint4 ov;
      ov.x = relu_pack(v1[it].x, v2[it].x, pa.x, pa.y);
      ov.y = relu_pack(v1[it].y, v2[it].y, pa.z, pa.w);
      ov.z = relu_pack(v1[it].z, v2[it].z, pc.x, pc.y);
      ov.w = relu_pack(v1[it].w, v2[it].w, pc.z, pc.w);
      *(uint4*)(t_lds + rstage*264 + c0) = ov;
    }
  }

  __syncthreads();   // t_lds + row_l/gate_l/mask_l visible to all waves

  f32x4 acc[4][2];
  for (int mi = 0; mi < 4; ++mi)
    for (int nj = 0; nj < 2; ++nj)
      acc[mi][nj] = (f32x4){0.f,0.f,0.f,0.f};

  const int sw = (g ^ ((lr >> 1) & 3)) << 3;

  // ---- GEMM2: barrier-free, wave-private double-buffered staging ----
  #pragma unroll
  for (int ks = 0; ks < 8; ++ks){
    if (ks >= 1 && ks < 7){
      #pragma unroll
      for (int j = 0; j < 2; ++j)
        gl_lds16(w2img + wbase + (size_t)((ks+1)*256 + w*32 + j*16)*32 + lane*8,
                 b_lds + ((ks+1)&1)*8192 + w*1024 + j*512);
      asm volatile("s_waitcnt vmcnt(2)" ::: "memory");
    } else if (ks == 0){
      asm volatile("s_waitcnt vmcnt(2)" ::: "memory");
    } else {
      asm volatile("s_waitcnt vmcnt(0)" ::: "memory");
    }
    const u16* bb = b_lds + (ks&1)*8192 + w*1024;
    bf16x8 af[4], bfr[2];
    for (int nj = 0; nj < 2; ++nj)
      bfr[nj] = *(const bf16x8*)(bb + (nj*16 + lr)*32 + sw);
    for (int mi = 0; mi < 4; ++mi)
      af[mi] = *(const bf16x8*)(t_lds + (mi*16 + lr)*264 + ks*32 + g*8);
    __builtin_amdgcn_s_setprio(1);
    for (int mi = 0; mi < 4; ++mi)
      for (int nj = 0; nj < 2; ++nj)
        acc[mi][nj] = __builtin_amdgcn_mfma_f32_16x16x32_bf16(af[mi], bfr[nj], acc[mi][nj], 0, 0, 0);
    __builtin_amdgcn_s_setprio(0);
  }

  // ---- epilogue: (+b2)*gate -> bf16 msgs, wave-private b_lds, b64 stores ----
  {
    float b2v[2];
    for (int nj = 0; nj < 2; ++nj) b2v[nj] = b2g[layer*HD + w*32 + nj*16 + lr];
    for (int mi = 0; mi < 4; ++mi)
      for (int nj = 0; nj < 2; ++nj){
        u16* mb = b_lds + nj*8192 + w*1024 + lr*64;
        float v[4];
        #pragma unroll
        for (int p = 0; p < 4; ++p){
          int re = mi*16 + g*4 + p;
          v[p] = (acc[mi][nj][p] + b2v[nj]) * gate_l[re];
        }
        int slot = (mi*2 + (g >> 1)) ^ (lr & 7);
        uint2 pkv; pkv.x = pk2t(v[0], v[1]); pkv.y = pk2t(v[2], v[3]);
        *(uint2*)(mb + slot*8 + (g & 1)*4) = pkv;
      }
  }
  __syncthreads();

  // ---- segmented reduction: wave-uniform mask flush (no per-element compare) ----
  {
    const int cl = tid & 255, half = tid >> 8;   // half uniform per wave
    u64 mk = mask_l;
    u32 m32 = (u32)(mk >> (half ? 32 : 0));
    m32 = __builtin_amdgcn_readfirstlane(m32);
    const u16* mb = b_lds + ((cl >> 4) & 1)*8192 + (cl >> 5)*1024 + (cl & 15)*64;
    float run = 0.f;
    #pragma unroll
    for (int e8l = 0; e8l < 4; ++e8l){
      int e8 = half*4 + e8l;
      bf16x8 mv = *(const bf16x8*)(mb + ((e8 ^ (cl & 7)) << 3));
      #pragma unroll
      for (int j = 0; j < 8; ++j){
        int el = e8l*8 + j;              // local edge 0..31
        run += bf2f((u16)mv[j]);
        bool fl = (el == 31) || ((m32 >> (el + 1)) & 1u);
        if (fl){
          int rr = row_l[half*32 + el];
          atomicAdd(h + (size_t)rr*HD + cl, run);
          run = 0.f;
        }
      }
    }
  }
}

// ---- column sums for pooling ----
__global__ void pool_k(const float* __restrict__ h,
                       float* __restrict__ pooled){
  int c = threadIdx.x;
  int r0 = blockIdx.x * 50;
  float s = 0.f;
  for (int r = r0; r < r0 + 50; ++r)
    s += h[(size_t)r*HD + c];
  atomicAdd(&pooled[c], s);
}

// ---- fg = mean(h) @ fg_w + fg_b (computed once) ----
__global__ void fg_k(const float* __restrict__ pooled,
                     const float* __restrict__ fg_w,
                     const float* __restrict__ fg_b,
                     float* __restrict__ fg_vals){
  int o = threadIdx.x;
  int k = o >> 4, j = o & 15;
  float s = 0.f;
  for (int d = 0; d < HD; ++d) s += pooled[d] * fg_w[(size_t)k*HD*16 + d*16 + j];
  fg_vals[o] = s / (float)NN + fg_b[k*16 + j];
}

__global__ void bcast_fg_k(const float* __restrict__ fg_vals,
                           float* __restrict__ out_fg){
  __shared__ float fv[64];
  if (threadIdx.x < 64) fv[threadIdx.x] = fg_vals[threadIdx.x];
  __syncthreads();
  int i = blockIdx.x*256 + threadIdx.x;
  out_fg[i] = fv[i & 63];
}

// ---- chemical properties MLP via MFMA ----
__launch_bounds__(256, 3)
__global__ void props_mfma_k(const float* __restrict__ h,
                             const u16* __restrict__ pw1bf,
                             const float* __restrict__ pb1,
                             const float* __restrict__ pw2,
                             const float* __restrict__ pb2,
                             float* __restrict__ outp){
  __shared__ u16 a_lds[64*40];
  __shared__ u16 b2_lds[128*40];
  __shared__ u16 t2[64*136];
  __shared__ float w2s[128*32];
  const int tid = threadIdx.x;
  const int n0 = blockIdx.x*64;
  const int w = tid >> 6, lane = tid & 63, g = lane >> 4, lr = lane & 15;
  const int rstage = tid >> 2, q = tid & 3;
  int arow = n0 + rstage; if (arow >= NN) arow = NN-1;
  const float* hrow = h + (size_t)arow*HD;

  for (int j = 0; j < 4; ++j)
    *(float4*)(w2s + tid*16 + j*4) = *(const float4*)(pw2 + tid*16 + j*4);

  const int colb = tid >> 1, halfb = tid & 1;

  f32x4 acc[4][2];
  for (int mi = 0; mi < 4; ++mi)
    for (int nj = 0; nj < 2; ++nj)
      acc[mi][nj] = (f32x4){0.f,0.f,0.f,0.f};

  for (int ks = 0; ks < 8; ++ks){
    __syncthreads();
    {
      const float* src = hrow + ks*32 + q*8;
      float4 f0 = *(const float4*)src;
      float4 f1 = *(const float4*)(src + 4);
      uint4 av;
      av.x = pk2(f0.x,f0.y); av.y = pk2(f0.z,f0.w);
      av.z = pk2(f1.x,f1.y); av.w = pk2(f1.z,f1.w);
      *(uint4*)(a_lds + rstage*40 + q*8) = av;
    }
    {
      const u16* src = pw1bf + colb*256 + ks*32 + halfb*16;
      uint4 s0 = *(const uint4*)src;
      uint4 s1 = *(const uint4*)(src + 8);
      u16* dst = b2_lds + colb*40 + halfb*16;
      *(uint4*)dst = s0; *(uint4*)(dst + 8) = s1;
    }
    __syncthreads();
    bf16x8 af[4], bfr[2];
    for (int mi = 0; mi < 4; ++mi)
      af[mi] = *(const bf16x8*)(a_lds + (mi*16 + lr)*40 + g*8);
    for (int nj = 0; nj < 2; ++nj)
      bfr[nj] = *(const bf16x8*)(b2_lds + (w*32 + nj*16 + lr)*40 + g*8);
    for (int mi = 0; mi < 4; ++mi)
      for (int nj = 0; nj < 2; ++nj)
        acc[mi][nj] = __builtin_amdgcn_mfma_f32_16x16x32_bf16(af[mi], bfr[nj], acc[mi][nj], 0, 0, 0);
  }

  {
    float b1v[2];
    for (int nj = 0; nj < 2; ++nj) b1v[nj] = pb1[w*32 + nj*16 + lr];
    for (int mi = 0; mi < 4; ++mi)
      for (int nj = 0; nj < 2; ++nj){
        int colt = w*32 + nj*16 + lr;
        for (int p = 0; p < 4; ++p){
          float v = acc[mi][nj][p] + b1v[nj];
          v = v > 0.f ? v : 0.f;
          t2[(mi*16 + g*4 + p)*136 + colt] = f2bf(v);
        }
      }
  }
  __syncthreads();

  {
    int e = tid >> 2, o0 = (tid & 3)*8;
    int n = n0 + e;
    float ap[8];
    #pragma unroll
    for (int o = 0; o < 8; ++o) ap[o] = pb2[o0 + o];
    for (int d0 = 0; d0 < 16; ++d0){
      bf16x8 tv = *(const bf16x8*)(t2 + e*136 + d0*8);
      #pragma unroll
      for (int dd = 0; dd < 8; ++dd){
        float t = bf2f((u16)tv[dd]);
        const float* wr = w2s + (d0*8 + dd)*32 + o0;
        #pragma unroll
        for (int o = 0; o < 8; ++o) ap[o] += t * wr[o];
      }
    }
    if (n < NN){
      *(float4*)(outp + (size_t)n*32 + o0)     = *(float4*)(ap);
      *(float4*)(outp + (size_t)n*32 + o0 + 4) = *(float4*)(ap + 4);
    }
  }
}

extern "C" void kernel_launch(void* const* d_in, const int* in_sizes, int n_in,
                              void* d_out, int out_size, void* d_ws, size_t ws_size,
                              hipStream_t stream) {
  const float* x            = (const float*)d_in[0];
  const int*   eidx         = (const int*)  d_in[1];
  const float* eattr        = (const float*)d_in[2];
  const float* atom_table   = (const float*)d_in[4];
  const float* charge_table = (const float*)d_in[5];
  const float* hybrid_table = (const float*)d_in[6];
  const float* bond_table   = (const float*)d_in[7];
  const float* gw1          = (const float*)d_in[8];
  const float* gb1          = (const float*)d_in[9];
  const float* gw2          = (const float*)d_in[10];
  const float* gb2          = (const float*)d_in[11];
  const float* attw         = (const float*)d_in[12];
  const float* attb         = (const float*)d_in[13];
  const float* pw1          = (const float*)d_in[14];
  const float* pb1          = (const float*)d_in[15];
  const float* pw2          = (const float*)d_in[16];
  const float* pb2          = (const float*)d_in[17];
  const float* fgw          = (const float*)d_in[18];
  const float* fgb          = (const float*)d_in[19];

  float* out       = (float*)d_out;
  float* out_h     = out;
  float* out_props = out + (size_t)NN*HD;
  float* out_fg    = out_props + (size_t)NN*32;
  float* out_at    = out_fg + (size_t)NN*64;

  char* ws = (char*)d_ws;
  u16*   pre      = (u16*)  (ws + WS_PRE);
  u16*   w1t      = (u16*)  (ws + WS_W1T);
  u16*   w2img    = (u16*)  (ws + WS_W2I);
  u16*   pw1bf    = (u16*)  (ws + WS_PW1);
  float* prebg    = (float*)(ws + WS_PREB);
  float* gate_tab = (float*)(ws + WS_GATE);
  float* pooled   = (float*)(ws + WS_POOL);
  float* fg_vals  = (float*)(ws + WS_FGV);
  int*   cnt      = (int*)  (ws + WS_CNT);
  int2*  smeta    = (int2*) (ws + WS_META);

  setup_k<<<5219, 256, 0, stream>>>(gw1, gw2, pw1, bond_table, gb1, attw, attb,
                                    x, atom_table, charge_table, hybrid_table,
                                    w1t, w2img, pw1bf, prebg, gate_tab, pooled,
                                    cnt, out_h, out_at);

  hist_k<<<1250, 256, 0, stream>>>(eidx, cnt);
  scan_k<<<1, 1024, 0, stream>>>(cnt);
  scatter_k<<<1250, 256, 0, stream>>>(eidx, eattr, cnt, smeta);

  for (int l = 0; l < 3; ++l){
    pre_k<<<dim3(313, 2), 256, 0, stream>>>(out_h, w1t, pre, l);
    edge_msg_k<<<5000, 512, 0, stream>>>(smeta, pre, prebg, w2img,
                                         gb2, gate_tab, out_h, l);
  }

  pool_k<<<400, 256, 0, stream>>>(out_h, pooled);
  fg_k<<<1, 64, 0, stream>>>(pooled, fgw, fgb, fg_vals);
  props_mfma_k<<<313, 256, 0, stream>>>(out_h, pw1bf, pb1, pw2, pb2, out_props);
  bcast_fg_k<<<5000, 256, 0, stream>>>(fg_vals, out_fg);
}